// Round 2
// baseline (4772.606 us; speedup 1.0000x reference)
//
#include <hip/hip_runtime.h>
#include <math.h>

// Problem dims
#define NB   16     // batch
#define SL   128    // seq len
#define ED   300    // word emb dim
#define HD   512    // lstm hidden
#define G4   2048   // 4*HD
#define NT   9      // tag count T
#define BE   64     // bio emb dim
#define RE   128    // REL_E
#define NR   50     // R
#define OCD  576    // HD + BE
#define NTOK 2048   // NB*SL

__device__ __forceinline__ float sigf(float x){ return 1.0f/(1.0f + __expf(-x)); }

// ---------------------------------------------------------------- generic fp32 GEMM body
template<int TM>
__device__ __forceinline__ void gemm_body(const float* __restrict__ A, int lda,
                                          const float* __restrict__ Bm, int ldb,
                                          float* __restrict__ C, int ldc,
                                          int N, int K,
                                          const float* __restrict__ bias1,
                                          const float* __restrict__ bias2,
                                          int do_relu, int m_blk, int n_blk)
{
    constexpr int TR = TM/16;
    __shared__ float As[16][TM+4];
    __shared__ float Bs[16][68];
    const int t = threadIdx.x;
    const int tm = (t >> 4) * TR;
    const int tn = (t & 15) * 4;
    float acc[TR][4];
    #pragma unroll
    for (int i=0;i<TR;++i){ acc[i][0]=0.f; acc[i][1]=0.f; acc[i][2]=0.f; acc[i][3]=0.f; }

    const int kc = (K + 15) >> 4;
    for (int ck = 0; ck < kc; ++ck){
        const int k0 = ck << 4;
        __syncthreads();
        #pragma unroll
        for (int it = 0; it < TM/64; ++it){
            int task = t + it*256;
            int m = task >> 2, q = task & 3;
            int kk = k0 + q*4;
            float4 v = make_float4(0.f,0.f,0.f,0.f);
            const float* ap = A + (size_t)(m_blk + m)*lda + kk;
            if (kk + 3 < K) v = *(const float4*)ap;
            else {
                if (kk   < K) v.x = ap[0];
                if (kk+1 < K) v.y = ap[1];
                if (kk+2 < K) v.z = ap[2];
            }
            As[q*4+0][m] = v.x; As[q*4+1][m] = v.y; As[q*4+2][m] = v.z; As[q*4+3][m] = v.w;
        }
        {
            int n = t >> 2, q = t & 3;
            int kk = k0 + q*4;
            int gn = n_blk + n;
            float4 v = make_float4(0.f,0.f,0.f,0.f);
            if (gn < N){
                const float* bp = Bm + (size_t)gn*ldb + kk;
                if (kk + 3 < K) v = *(const float4*)bp;
                else {
                    if (kk   < K) v.x = bp[0];
                    if (kk+1 < K) v.y = bp[1];
                    if (kk+2 < K) v.z = bp[2];
                }
            }
            Bs[q*4+0][n] = v.x; Bs[q*4+1][n] = v.y; Bs[q*4+2][n] = v.z; Bs[q*4+3][n] = v.w;
        }
        __syncthreads();
        #pragma unroll
        for (int k = 0; k < 16; ++k){
            float4 b4 = *(const float4*)&Bs[k][tn];
            float bn[4] = {b4.x, b4.y, b4.z, b4.w};
            #pragma unroll
            for (int i = 0; i < TR/4; ++i){
                float4 a4 = *(const float4*)&As[k][tm + i*4];
                float am[4] = {a4.x, a4.y, a4.z, a4.w};
                #pragma unroll
                for (int mm = 0; mm < 4; ++mm){
                    #pragma unroll
                    for (int nn = 0; nn < 4; ++nn)
                        acc[i*4+mm][nn] += am[mm]*bn[nn];
                }
            }
        }
    }
    float bv[4];
    #pragma unroll
    for (int nn=0;nn<4;++nn){
        int gn = n_blk + tn + nn;
        float bb = 0.f;
        if (gn < N){
            if (bias1) bb += bias1[gn];
            if (bias2) bb += bias2[gn];
        }
        bv[nn] = bb;
    }
    bool vec = ((ldc & 3) == 0) && (n_blk + tn + 3 < N);
    #pragma unroll
    for (int mm = 0; mm < TR; ++mm){
        int gm = m_blk + tm + mm;
        float r0 = acc[mm][0] + bv[0];
        float r1 = acc[mm][1] + bv[1];
        float r2 = acc[mm][2] + bv[2];
        float r3 = acc[mm][3] + bv[3];
        if (do_relu){ r0=fmaxf(r0,0.f); r1=fmaxf(r1,0.f); r2=fmaxf(r2,0.f); r3=fmaxf(r3,0.f); }
        if (vec){
            *(float4*)(C + (size_t)gm*ldc + n_blk + tn) = make_float4(r0,r1,r2,r3);
        } else {
            int gn = n_blk + tn;
            if (gn   < N) C[(size_t)gm*ldc + gn  ] = r0;
            if (gn+1 < N) C[(size_t)gm*ldc + gn+1] = r1;
            if (gn+2 < N) C[(size_t)gm*ldc + gn+2] = r2;
            if (gn+3 < N) C[(size_t)gm*ldc + gn+3] = r3;
        }
    }
}

template<int TM>
__global__ __launch_bounds__(256) void gemm_k(const float* __restrict__ A, int lda,
                                              const float* __restrict__ Bm, int ldb,
                                              float* __restrict__ C, int ldc,
                                              int N, int K,
                                              const float* __restrict__ bias1,
                                              const float* __restrict__ bias2,
                                              int do_relu)
{
    gemm_body<TM>(A, lda, Bm, ldb, C, ldc, N, K, bias1, bias2, do_relu,
                  blockIdx.x * TM, blockIdx.y * 64);
}

template<int TM>
__global__ __launch_bounds__(256) void gemm_dual_k(const float* __restrict__ A0, const float* __restrict__ A1, int lda,
                                                   const float* __restrict__ B0, const float* __restrict__ B1, int ldb,
                                                   float* __restrict__ C0, float* __restrict__ C1, int ldc,
                                                   int N, int K,
                                                   const float* __restrict__ bias0, const float* __restrict__ bias1,
                                                   int do_relu)
{
    const int z = blockIdx.z;
    gemm_body<TM>(z ? A1 : A0, lda, z ? B1 : B0, ldb, z ? C1 : C0, ldc, N, K,
                  z ? bias1 : bias0, nullptr, do_relu, blockIdx.x * TM, blockIdx.y * 64);
}

// ---------------------------------------------------------------- xW GEMM with fused token-gather
__global__ __launch_bounds__(256) void gemm_emb_k(const int* __restrict__ tokens,
                                                  const float* __restrict__ word_emb,
                                                  const float* __restrict__ B0, const float* __restrict__ B1,
                                                  float* __restrict__ C0, float* __restrict__ C1,
                                                  const float* __restrict__ bi0a, const float* __restrict__ bi0b,
                                                  const float* __restrict__ bi1a, const float* __restrict__ bi1b)
{
    __shared__ float As[16][132];
    __shared__ float Bs[16][68];
    const int z = blockIdx.z;
    const float* Bm = z ? B1 : B0;
    float* C       = z ? C1 : C0;
    const float* ba = z ? bi1a : bi0a;
    const float* bb = z ? bi1b : bi0b;
    const int t = threadIdx.x;
    const int m_blk = blockIdx.x * 128;
    const int n_blk = blockIdx.y * 64;
    const int tm = (t >> 4) * 8;
    const int tn = (t & 15) * 4;
    float acc[8][4];
    #pragma unroll
    for (int i=0;i<8;++i){ acc[i][0]=0.f; acc[i][1]=0.f; acc[i][2]=0.f; acc[i][3]=0.f; }

    for (int ck = 0; ck < 19; ++ck){
        const int k0 = ck << 4;
        __syncthreads();
        #pragma unroll
        for (int it = 0; it < 2; ++it){
            int task = t + it*256;
            int m = task >> 2, q = task & 3;
            int kk = k0 + q*4;
            const int tok = tokens[m_blk + m];
            const float* ap = word_emb + (size_t)tok*ED + kk;
            float4 v = make_float4(0.f,0.f,0.f,0.f);
            if (kk + 3 < ED) v = *(const float4*)ap;
            else {
                if (kk   < ED) v.x = ap[0];
                if (kk+1 < ED) v.y = ap[1];
                if (kk+2 < ED) v.z = ap[2];
            }
            As[q*4+0][m] = v.x; As[q*4+1][m] = v.y; As[q*4+2][m] = v.z; As[q*4+3][m] = v.w;
        }
        {
            int n = t >> 2, q = t & 3;
            int kk = k0 + q*4;
            const float* bp = Bm + (size_t)(n_blk + n)*ED + kk;
            float4 v = make_float4(0.f,0.f,0.f,0.f);
            if (kk + 3 < ED) v = *(const float4*)bp;
            else {
                if (kk   < ED) v.x = bp[0];
                if (kk+1 < ED) v.y = bp[1];
                if (kk+2 < ED) v.z = bp[2];
            }
            Bs[q*4+0][n] = v.x; Bs[q*4+1][n] = v.y; Bs[q*4+2][n] = v.z; Bs[q*4+3][n] = v.w;
        }
        __syncthreads();
        #pragma unroll
        for (int k = 0; k < 16; ++k){
            float4 b4 = *(const float4*)&Bs[k][tn];
            float bn[4] = {b4.x, b4.y, b4.z, b4.w};
            #pragma unroll
            for (int i = 0; i < 2; ++i){
                float4 a4 = *(const float4*)&As[k][tm + i*4];
                float am[4] = {a4.x, a4.y, a4.z, a4.w};
                #pragma unroll
                for (int mm = 0; mm < 4; ++mm){
                    #pragma unroll
                    for (int nn = 0; nn < 4; ++nn)
                        acc[i*4+mm][nn] += am[mm]*bn[nn];
                }
            }
        }
    }
    float bv[4];
    #pragma unroll
    for (int nn=0;nn<4;++nn){ int gn = n_blk + tn + nn; bv[nn] = ba[gn] + bb[gn]; }
    #pragma unroll
    for (int mm = 0; mm < 8; ++mm){
        int gm = m_blk + tm + mm;
        *(float4*)(C + (size_t)gm*G4 + n_blk + tn) =
            make_float4(acc[mm][0]+bv[0], acc[mm][1]+bv[1], acc[mm][2]+bv[2], acc[mm][3]+bv[3]);
    }
}

// ---------------------------------------------------------------- intra-XCD L2 exchange primitives
// CDNA L1 is write-through: a store lands in the XCD L2; a load with sc0
// (L1-bypass) reads the XCD L2 directly. Producer+consumer on the SAME XCD
// => coherent exchange at L2 latency (~250 cyc) instead of Infinity-Cache
// latency (agent-scope path). Correctness does NOT depend on placement:
// producers dual-store (primary sc0 + agent-scope shadow), consumers fall
// back (sticky) to the shadow poll on timeout, and per-launch-unique tags
// make stale-line acceptance impossible.
// NOTE: global_load imm offset is 13-bit SIGNED (max +4095) -> use two base
// pointers (p, p+512 u64) with offsets {0, 512} only.
#define SHADOW_OFF 32768   // u64 offset of shadow region (8*2*2*1024)
#define SPIN_MAX   512

__device__ __forceinline__ void poll4_sc0(const unsigned long long* p,
                                          const unsigned long long* p2,
                                          unsigned long long& v0, unsigned long long& v1,
                                          unsigned long long& v2, unsigned long long& v3)
{
    asm volatile(
        "global_load_dwordx2 %0, %4, off sc0\n\t"
        "global_load_dwordx2 %1, %4, off offset:512 sc0\n\t"
        "global_load_dwordx2 %2, %5, off sc0\n\t"
        "global_load_dwordx2 %3, %5, off offset:512 sc0\n\t"
        "s_waitcnt vmcnt(0)"
        : "=&v"(v0), "=&v"(v1), "=&v"(v2), "=&v"(v3)
        : "v"(p), "v"(p2)
        : "memory");
}

__device__ __forceinline__ void st_sc0(unsigned long long* p, unsigned long long v)
{
    asm volatile("global_store_dwordx2 %0, %1, off sc0" :: "v"(p), "v"(v) : "memory");
}

// ---------------------------------------------------------------- direction-interleaved LSTM
// 8 teams of 32 wgs; team = batch-pair (2 batches), BOTH directions per wg.
// team = blockIdx & 7 so (under round-robin block->XCD dispatch) all 32
// wgs of a team share one XCD; the h exchange then stays in that XCD's L2
// via sc0 loads/stores. Agent-scope shadow + sticky fallback keeps it
// correct under any placement. Tags are (launch_base + step) so lines left
// over from a previous graph replay can never be mistaken for fresh data.
__global__ __launch_bounds__(256, 1) void lstm_k(const float* __restrict__ xwf,
                                                 const float* __restrict__ xwb,
                                                 const float* __restrict__ whhf,
                                                 const float* __restrict__ whhb,
                                                 unsigned long long* __restrict__ hteam, // 2*(8*2*2*1024) u64 (primary+shadow)
                                                 float* __restrict__ hf_all,
                                                 float* __restrict__ hb_all,
                                                 const unsigned* __restrict__ lcnt)
{
    __shared__ __align__(16) float h_sf[2*HD];     // 4 KB
    __shared__ __align__(16) float h_sb[2*HD];     // 4 KB
    __shared__ __align__(16) float part[8*128];    // 4 KB [kc][row*2+b]
    __shared__ float gates_s[128];                 // [row*2+b]
    __shared__ float cst[64];                      // [dir*32 + hid*2 + b]
    const int wg   = blockIdx.x;
    const int team = wg & 7;       // XCD-local team (blocks round-robin XCDs)
    const int rank = wg >> 3;
    const int b0   = team * 2;
    const int t    = threadIdx.x;
    const int wv   = t >> 6;
    const int lane = t & 63;
    const int rg   = t & 31;
    const int kc   = t >> 5;                       // 0..7 (64 k each)
    const int lr0  = rg*2, lr1 = rg*2 + 1;
    const int grow0 = (lr0 >> 4)*HD + rank*16 + (lr0 & 15);
    const int grow1 = (lr1 >> 4)*HD + rank*16 + (lr1 & 15);
    unsigned long long* hTf = hteam + (size_t)(team*2 + 0)*2*1024;
    unsigned long long* hTb = hteam + (size_t)(team*2 + 1)*2*1024;

    // per-launch unique tag base (bumped by finalize_k of the previous launch)
    const unsigned base = (__hip_atomic_load(lcnt, __ATOMIC_RELAXED, __HIP_MEMORY_SCOPE_AGENT)
                           & 0xFFFFFFu) * 130u + 1u;

    // ---- one-time: both dirs' weight slices into registers (64 float4 = 256 VGPRs) ----
    float4 wf0[16], wf1[16], wb0[16], wb1[16];
    {
        const float* p0 = whhf + (size_t)grow0*HD + kc*64;
        const float* p1 = whhf + (size_t)grow1*HD + kc*64;
        const float* p2 = whhb + (size_t)grow0*HD + kc*64;
        const float* p3 = whhb + (size_t)grow1*HD + kc*64;
        #pragma unroll
        for (int q = 0; q < 16; ++q){
            wf0[q] = *(const float4*)(p0 + q*4);
            wf1[q] = *(const float4*)(p1 + q*4);
            wb0[q] = *(const float4*)(p2 + q*4);
            wb1[q] = *(const float4*)(p3 + q*4);
        }
    }
    // reduce mapping (t<128): entry = row*2 + b
    const int rrow = t >> 1, rb2 = t & 1;
    const int growr = (rrow >> 4)*HD + rank*16 + (rrow & 15);
    // activation mapping (t<32)
    const int ahl = t >> 1, ab2 = t & 1;
    const int hidx_a = rank*16 + ahl;
    // staging slots (4 u64/thread/dir): b in {0,1}, halves {0,64}
    const int s0 = wv*128 + lane;

    if (t < 64) cst[t] = 0.f;
    __syncthreads();

    int to_f = 0, to_b = 0;    // sticky timeout counters (>=3 => agent/shadow path)
    int par = 0;
    for (int s = 0; s < SL; ++s){
        const unsigned want = s ? (base + (unsigned)s) : 0u;  // s=0 comes from memset(0)
        float xval_f = 0.f, xval_b = 0.f;
        if (t < 128){
            xval_f = xwf[(size_t)((b0 + rb2)*SL + s)*G4 + growr];
            xval_b = xwb[(size_t)((b0 + rb2)*SL + (SL-1 - s))*G4 + growr];
        }
        // ---- 1. poll + stage fwd ----
        {
            unsigned long long v0=0, v1=0, v2=0, v3=0;
            bool got = false;
            if (to_f < 3){
                const unsigned long long* src  = hTf + (size_t)par*1024 + s0;
                const unsigned long long* src2 = src + 512;
                int spins = 0;
                for (;;){
                    poll4_sc0(src, src2, v0, v1, v2, v3);
                    if (((unsigned)(v0>>32)==want) & ((unsigned)(v1>>32)==want) &
                        ((unsigned)(v2>>32)==want) & ((unsigned)(v3>>32)==want)){ got = true; break; }
                    if (++spins >= SPIN_MAX){ ++to_f; break; }
                }
            }
            if (!got){
                const unsigned long long* src = hTf + SHADOW_OFF + (size_t)par*1024;
                for (;;){
                    v0 = __hip_atomic_load(&src[      s0     ], __ATOMIC_RELAXED, __HIP_MEMORY_SCOPE_AGENT);
                    v1 = __hip_atomic_load(&src[      s0 + 64], __ATOMIC_RELAXED, __HIP_MEMORY_SCOPE_AGENT);
                    v2 = __hip_atomic_load(&src[512 + s0     ], __ATOMIC_RELAXED, __HIP_MEMORY_SCOPE_AGENT);
                    v3 = __hip_atomic_load(&src[512 + s0 + 64], __ATOMIC_RELAXED, __HIP_MEMORY_SCOPE_AGENT);
                    if (((unsigned)(v0>>32)==want) & ((unsigned)(v1>>32)==want) &
                        ((unsigned)(v2>>32)==want) & ((unsigned)(v3>>32)==want)) break;
                    __builtin_amdgcn_s_sleep(1);
                }
            }
            h_sf[     s0     ] = __uint_as_float((unsigned)v0);
            h_sf[     s0 + 64] = __uint_as_float((unsigned)v1);
            h_sf[HD + s0     ] = __uint_as_float((unsigned)v2);
            h_sf[HD + s0 + 64] = __uint_as_float((unsigned)v3);
        }
        // ---- 2. bwd shadow prefetch (slow mode only; fast mode polls L2 after fwd compute) ----
        const bool preb = (to_b >= 3);
        const unsigned long long* srcb_sh = hTb + SHADOW_OFF + (size_t)par*1024;
        unsigned long long p0=0, p1=0, p2=0, p3=0;
        if (preb){
            p0 = __hip_atomic_load(&srcb_sh[      s0     ], __ATOMIC_RELAXED, __HIP_MEMORY_SCOPE_AGENT);
            p1 = __hip_atomic_load(&srcb_sh[      s0 + 64], __ATOMIC_RELAXED, __HIP_MEMORY_SCOPE_AGENT);
            p2 = __hip_atomic_load(&srcb_sh[512 + s0     ], __ATOMIC_RELAXED, __HIP_MEMORY_SCOPE_AGENT);
            p3 = __hip_atomic_load(&srcb_sh[512 + s0 + 64], __ATOMIC_RELAXED, __HIP_MEMORY_SCOPE_AGENT);
        }
        // ---- 3. fwd partials: 2 rows x 2 batches x 64 k ----
        {
            float a00=0.f,a01=0.f,a10=0.f,a11=0.f;
            #pragma unroll
            for (int q = 0; q < 16; ++q){
                float4 wa = wf0[q], wb = wf1[q];
                float4 h0 = *(const float4*)(h_sf + 0*HD + kc*64 + q*4);
                float4 h1 = *(const float4*)(h_sf + 1*HD + kc*64 + q*4);
                a00 += wa.x*h0.x + wa.y*h0.y + wa.z*h0.z + wa.w*h0.w;
                a01 += wa.x*h1.x + wa.y*h1.y + wa.z*h1.z + wa.w*h1.w;
                a10 += wb.x*h0.x + wb.y*h0.y + wb.z*h0.z + wb.w*h0.w;
                a11 += wb.x*h1.x + wb.y*h1.y + wb.z*h1.z + wb.w*h1.w;
            }
            *(float4*)&part[kc*128 + lr0*2] = make_float4(a00,a01,a10,a11);
        }
        __syncthreads();
        if (t < 128){
            float g = 0.f;
            #pragma unroll
            for (int c = 0; c < 8; ++c) g += part[c*128 + t];
            gates_s[t] = g + xval_f;
        }
        __syncthreads();
        if (t < 32){
            float gi = gates_s[(0*16 + ahl)*2 + ab2];
            float gf = gates_s[(1*16 + ahl)*2 + ab2];
            float gc = gates_s[(2*16 + ahl)*2 + ab2];
            float go_ = gates_s[(3*16 + ahl)*2 + ab2];
            float cp = cst[t];
            float cn = sigf(gf)*cp + sigf(gi)*tanhf(gc);
            float hn = sigf(go_)*tanhf(cn);
            cst[t] = cn;
            unsigned long long pk = ((unsigned long long)(base + (unsigned)(s+1)) << 32)
                                  | (unsigned long long)__float_as_uint(hn);
            const size_t off = (size_t)(par^1)*1024 + ab2*512 + hidx_a;
            st_sc0(&hTf[off], pk);
            __hip_atomic_store(&hTf[SHADOW_OFF + off], pk,
                               __ATOMIC_RELAXED, __HIP_MEMORY_SCOPE_AGENT);
            hf_all[(size_t)((b0 + ab2)*SL + s)*HD + hidx_a] = hn;
        }
        // ---- 4. poll + stage bwd (fast: L2 poll now; slow: check prefetch, spin shadow) ----
        {
            unsigned long long w0=p0, w1=p1, w2=p2, w3=p3;
            bool got = false;
            if (!preb){
                const unsigned long long* srcb  = hTb + (size_t)par*1024 + s0;
                const unsigned long long* srcb2 = srcb + 512;
                int spins = 0;
                for (;;){
                    poll4_sc0(srcb, srcb2, w0, w1, w2, w3);
                    if (((unsigned)(w0>>32)==want) & ((unsigned)(w1>>32)==want) &
                        ((unsigned)(w2>>32)==want) & ((unsigned)(w3>>32)==want)){ got = true; break; }
                    if (++spins >= SPIN_MAX){ ++to_b; break; }
                }
            } else {
                if (((unsigned)(w0>>32)==want) & ((unsigned)(w1>>32)==want) &
                    ((unsigned)(w2>>32)==want) & ((unsigned)(w3>>32)==want)) got = true;
            }
            if (!got){
                for (;;){
                    w0 = __hip_atomic_load(&srcb_sh[      s0     ], __ATOMIC_RELAXED, __HIP_MEMORY_SCOPE_AGENT);
                    w1 = __hip_atomic_load(&srcb_sh[      s0 + 64], __ATOMIC_RELAXED, __HIP_MEMORY_SCOPE_AGENT);
                    w2 = __hip_atomic_load(&srcb_sh[512 + s0     ], __ATOMIC_RELAXED, __HIP_MEMORY_SCOPE_AGENT);
                    w3 = __hip_atomic_load(&srcb_sh[512 + s0 + 64], __ATOMIC_RELAXED, __HIP_MEMORY_SCOPE_AGENT);
                    if (((unsigned)(w0>>32)==want) & ((unsigned)(w1>>32)==want) &
                        ((unsigned)(w2>>32)==want) & ((unsigned)(w3>>32)==want)) break;
                    __builtin_amdgcn_s_sleep(1);
                }
            }
            h_sb[     s0     ] = __uint_as_float((unsigned)w0);
            h_sb[     s0 + 64] = __uint_as_float((unsigned)w1);
            h_sb[HD + s0     ] = __uint_as_float((unsigned)w2);
            h_sb[HD + s0 + 64] = __uint_as_float((unsigned)w3);
        }
        // ---- 5. bwd partials ----
        {
            float a00=0.f,a01=0.f,a10=0.f,a11=0.f;
            #pragma unroll
            for (int q = 0; q < 16; ++q){
                float4 wa = wb0[q], wb = wb1[q];
                float4 h0 = *(const float4*)(h_sb + 0*HD + kc*64 + q*4);
                float4 h1 = *(const float4*)(h_sb + 1*HD + kc*64 + q*4);
                a00 += wa.x*h0.x + wa.y*h0.y + wa.z*h0.z + wa.w*h0.w;
                a01 += wa.x*h1.x + wa.y*h1.y + wa.z*h1.z + wa.w*h1.w;
                a10 += wb.x*h0.x + wb.y*h0.y + wb.z*h0.z + wb.w*h0.w;
                a11 += wb.x*h1.x + wb.y*h1.y + wb.z*h1.z + wb.w*h1.w;
            }
            *(float4*)&part[kc*128 + lr0*2] = make_float4(a00,a01,a10,a11);
        }
        __syncthreads();
        if (t < 128){
            float g = 0.f;
            #pragma unroll
            for (int c = 0; c < 8; ++c) g += part[c*128 + t];
            gates_s[t] = g + xval_b;
        }
        __syncthreads();
        if (t < 32){
            float gi = gates_s[(0*16 + ahl)*2 + ab2];
            float gf = gates_s[(1*16 + ahl)*2 + ab2];
            float gc = gates_s[(2*16 + ahl)*2 + ab2];
            float go_ = gates_s[(3*16 + ahl)*2 + ab2];
            float cp = cst[32 + t];
            float cn = sigf(gf)*cp + sigf(gi)*tanhf(gc);
            float hn = sigf(go_)*tanhf(cn);
            cst[32 + t] = cn;
            unsigned long long pk = ((unsigned long long)(base + (unsigned)(s+1)) << 32)
                                  | (unsigned long long)__float_as_uint(hn);
            const size_t off = (size_t)(par^1)*1024 + ab2*512 + hidx_a;
            st_sc0(&hTb[off], pk);
            __hip_atomic_store(&hTb[SHADOW_OFF + off], pk,
                               __ATOMIC_RELAXED, __HIP_MEMORY_SCOPE_AGENT);
            hb_all[(size_t)((b0 + ab2)*SL + (SL-1 - s))*HD + hidx_a] = hn;
        }
        par ^= 1;
    }
}

// ---------------------------------------------------------------- combine o | bio_emb
__global__ __launch_bounds__(256) void combine_k(const float* __restrict__ hf,
                                                 const float* __restrict__ hb,
                                                 const int* __restrict__ bio_gold,
                                                 const float* __restrict__ bio_emb,
                                                 float* __restrict__ oc)
{
    int idx = blockIdx.x*256 + threadIdx.x;
    if (idx >= NTOK*144) return;
    int row = idx / 144;
    int c4 = (idx - row*144) * 4;
    float4 v;
    if (c4 < HD){
        float4 a = *(const float4*)(hf + (size_t)row*HD + c4);
        float4 b = *(const float4*)(hb + (size_t)row*HD + c4);
        v = make_float4(0.5f*(a.x+b.x), 0.5f*(a.y+b.y), 0.5f*(a.z+b.z), 0.5f*(a.w+b.w));
    } else {
        int bg = bio_gold[row];
        v = *(const float4*)(bio_emb + bg*BE + (c4 - HD));
    }
    *(float4*)(oc + (size_t)row*OCD + c4) = v;
}

// ---------------------------------------------------------------- CRF NLL (wave-sync) + msum
__global__ __launch_bounds__(64) void crf_k(const float* __restrict__ emi,
                                            const int* __restrict__ tags,
                                            const int* __restrict__ tokens,
                                            const float* __restrict__ trans,
                                            const float* __restrict__ startv,
                                            const float* __restrict__ endv,
                                            float* __restrict__ out_crf,
                                            float* __restrict__ out_m)
{
    const int b = blockIdx.x, lane = threadIdx.x;
    unsigned long long m0 = __ballot(tokens[b*SL + lane] != 0);
    unsigned long long m1 = __ballot(tokens[b*SL + 64 + lane] != 0);
    const int len = __popcll(m0) + __popcll(m1);
    float npart = 0.f;
    #pragma unroll
    for (int half = 0; half < 2; ++half){
        int tt = lane + half*64;
        if (tt >= 1 && tt < len){
            int tp = tags[b*SL + tt - 1], tc = tags[b*SL + tt];
            npart += trans[tp*NT + tc] + emi[(size_t)(b*SL + tt)*NT + tc];
        }
    }
    #pragma unroll
    for (int off = 32; off > 0; off >>= 1) npart += __shfl_down(npart, off);
    float tr[NT]; float alpha = -1e30f;
    if (lane < NT){
        #pragma unroll
        for (int i = 0; i < NT; ++i) tr[i] = trans[i*NT + lane];
        alpha = startv[lane] + emi[(size_t)(b*SL)*NT + lane];
    }
    for (int tt = 1; tt < SL; ++tt){
        float al[NT];
        #pragma unroll
        for (int i = 0; i < NT; ++i) al[i] = __shfl(alpha, i);
        if (lane < NT && tt < len){
            float mx = -1e30f;
            #pragma unroll
            for (int i = 0; i < NT; ++i) mx = fmaxf(mx, al[i] + tr[i]);
            float se = 0.f;
            #pragma unroll
            for (int i = 0; i < NT; ++i) se += __expf(al[i] + tr[i] - mx);
            alpha = mx + __logf(se) + emi[(size_t)(b*SL + tt)*NT + lane];
        }
    }
    float alf = (lane < NT) ? (alpha + endv[lane]) : -1e30f;
    float alE[NT];
    #pragma unroll
    for (int i = 0; i < NT; ++i) alE[i] = __shfl(alf, i);
    if (lane == 0){
        float mx = -1e30f;
        #pragma unroll
        for (int i = 0; i < NT; ++i) mx = fmaxf(mx, alE[i]);
        float se = 0.f;
        #pragma unroll
        for (int i = 0; i < NT; ++i) se += __expf(alE[i] - mx);
        float den = mx + __logf(se);
        int t0g = tags[b*SL];
        float num = startv[t0g] + emi[(size_t)(b*SL)*NT + t0g] + npart;
        num += endv[tags[b*SL + len - 1]];
        atomicAdd(out_crf, -(num - den) * (1.0f/16.0f));
        atomicAdd(out_m, (float)len);
    }
}

// ---------------------------------------------------------------- fused uv->logits->BCE
__global__ __launch_bounds__(256) void sel_k(const float* __restrict__ U2,
                                             const float* __restrict__ V2,
                                             const float* __restrict__ uvb,
                                             const float* __restrict__ rel_emb,
                                             const int* __restrict__ gold,
                                             const int* __restrict__ tokens,
                                             float* __restrict__ out_sel)
{
    __shared__ float ret_s[RE][52];
    __shared__ float pt_s[RE][68];
    __shared__ float vb_s[RE];
    __shared__ float mk_s[64];
    __shared__ float red_s[4];
    const int jt = blockIdx.x, qi = blockIdx.y, b = blockIdx.z;
    const int t = threadIdx.x;
    if (tokens[b*SL + qi] == 0) return;
    if (t < 32){
        float4 v4 = *(const float4*)(V2 + (size_t)(b*SL + qi)*RE + t*4);
        float4 b4 = *(const float4*)(uvb + t*4);
        vb_s[t*4+0] = v4.x + b4.x; vb_s[t*4+1] = v4.y + b4.y;
        vb_s[t*4+2] = v4.z + b4.z; vb_s[t*4+3] = v4.w + b4.w;
    }
    if (t < 64) mk_s[t] = (tokens[b*SL + jt*64 + t] != 0) ? 1.f : 0.f;
    {
        int r = t & 63;
        for (int q = t >> 6; q < 32; q += 4){
            if (r < NR){
                float4 e4 = *(const float4*)(rel_emb + (size_t)r*RE + q*4);
                ret_s[q*4+0][r] = e4.x; ret_s[q*4+1][r] = e4.y;
                ret_s[q*4+2][r] = e4.z; ret_s[q*4+3][r] = e4.w;
            } else if (r < 64){
                ret_s[q*4+0][r] = 0.f; ret_s[q*4+1][r] = 0.f;
                ret_s[q*4+2][r] = 0.f; ret_s[q*4+3][r] = 0.f;
            }
        }
    }
    __syncthreads();
    {
        int j = t & 63;
        for (int q = t >> 6; q < 32; q += 4){
            float4 u4 = *(const float4*)(U2 + (size_t)(b*SL + jt*64 + j)*RE + q*4);
            pt_s[q*4+0][j] = fmaxf(u4.x + vb_s[q*4+0], 0.f);
            pt_s[q*4+1][j] = fmaxf(u4.y + vb_s[q*4+1], 0.f);
            pt_s[q*4+2][j] = fmaxf(u4.z + vb_s[q*4+2], 0.f);
            pt_s[q*4+3][j] = fmaxf(u4.w + vb_s[q*4+3], 0.f);
        }
    }
    __syncthreads();
    const int mj = (t & 15) * 4;
    const int nr = (t >> 4) * 4;
    float accv[4][4];
    #pragma unroll
    for (int i=0;i<4;++i){ accv[i][0]=0.f; accv[i][1]=0.f; accv[i][2]=0.f; accv[i][3]=0.f; }
    #pragma unroll 4
    for (int k = 0; k < RE; ++k){
        float4 aj = *(const float4*)&pt_s[k][mj];
        float4 br = *(const float4*)&ret_s[k][nr];
        float am[4] = {aj.x, aj.y, aj.z, aj.w};
        float bn[4] = {br.x, br.y, br.z, br.w};
        #pragma unroll
        for (int mm = 0; mm < 4; ++mm){
            #pragma unroll
            for (int nn = 0; nn < 4; ++nn)
                accv[mm][nn] += am[mm]*bn[nn];
        }
    }
    float lsum = 0.f;
    #pragma unroll
    for (int nn = 0; nn < 4; ++nn){
        int r = nr + nn;
        if (r < NR){
            const int* gp = gold + (size_t)((b*SL + qi)*NR + r)*SL + jt*64 + mj;
            #pragma unroll
            for (int mm = 0; mm < 4; ++mm){
                float l = accv[mm][nn];
                float g = (float)gp[mm];
                float bce = fmaxf(l, 0.f) - l*g + __logf(1.f + __expf(-fabsf(l)));
                lsum += bce * mk_s[mj + mm];
            }
        }
    }
    #pragma unroll
    for (int off = 32; off > 0; off >>= 1) lsum += __shfl_down(lsum, off);
    if ((t & 63) == 0) red_s[t >> 6] = lsum;
    __syncthreads();
    if (t == 0) atomicAdd(out_sel, red_s[0]+red_s[1]+red_s[2]+red_s[3]);
}

// ---------------------------------------------------------------- finalize (+ launch counter bump)
__global__ void finalize_k(const float* __restrict__ accum, float* __restrict__ out,
                           unsigned* __restrict__ lcnt)
{
    if (threadIdx.x == 0 && blockIdx.x == 0){
        out[0] = accum[0] + accum[1] / accum[2];
        __hip_atomic_fetch_add(lcnt, 1u, __ATOMIC_RELAXED, __HIP_MEMORY_SCOPE_AGENT);
    }
}

// ---------------------------------------------------------------- launch
extern "C" void kernel_launch(void* const* d_in, const int* in_sizes, int n_in,
                              void* d_out, int out_size, void* d_ws, size_t ws_size,
                              hipStream_t stream)
{
    const int*   tokens    = (const int*)  d_in[0];
    const int*   bio_gold  = (const int*)  d_in[1];
    const int*   sel_gold  = (const int*)  d_in[2];
    const float* word_emb  = (const float*)d_in[4];
    const float* rel_emb   = (const float*)d_in[5];
    const float* bio_emb   = (const float*)d_in[6];
    const float* w_ih_f    = (const float*)d_in[7];
    const float* w_hh_f    = (const float*)d_in[8];
    const float* b_ih_f    = (const float*)d_in[9];
    const float* b_hh_f    = (const float*)d_in[10];
    const float* w_ih_b    = (const float*)d_in[11];
    const float* w_hh_b    = (const float*)d_in[12];
    const float* b_ih_b    = (const float*)d_in[13];
    const float* b_hh_b    = (const float*)d_in[14];
    const float* emission_w= (const float*)d_in[15];
    const float* emission_b= (const float*)d_in[16];
    const float* sel_u_w   = (const float*)d_in[17];
    const float* sel_u_b   = (const float*)d_in[18];
    const float* sel_v_w   = (const float*)d_in[19];
    const float* sel_v_b   = (const float*)d_in[20];
    const float* sel_uv_w  = (const float*)d_in[21];
    const float* sel_uv_b  = (const float*)d_in[22];
    const float* crf_trans = (const float*)d_in[23];
    const float* crf_start = (const float*)d_in[24];
    const float* crf_end   = (const float*)d_in[25];
    (void)in_sizes; (void)n_in; (void)out_size; (void)ws_size;

    float* ws     = (float*)d_ws;
    float* emb    = ws;                         // region reused for hteam
    float* xwf    = emb    + (size_t)NTOK*ED;
    float* xwb    = xwf    + (size_t)NTOK*G4;
    float* hf_all = xwb    + (size_t)NTOK*G4;
    float* hb_all = hf_all + (size_t)NTOK*HD;
    float* oc     = hb_all + (size_t)NTOK*HD;
    float* emi    = oc     + (size_t)NTOK*OCD;
    float* u_     = emi    + (size_t)NTOK*NT;
    float* v_     = u_     + (size_t)NTOK*RE;
    float* U2     = v_     + (size_t)NTOK*RE;
    float* V2     = U2     + (size_t)NTOK*RE;
    float* accum  = V2     + (size_t)NTOK*RE;   // [0]=crf, [1]=sel_sum, [2]=msum, [3]=pad
    unsigned* lcnt = (unsigned*)(accum + 4);    // persistent launch counter (NOT memset)

    // packed h exchange: primary (8 teams x 2 dirs x 2 par x 1024 u64) + shadow = 512 KB
    unsigned long long* hteam = (unsigned long long*)emb;

    hipMemsetAsync(accum, 0, 4*sizeof(float), stream);
    hipMemsetAsync(hteam, 0, (size_t)2*8*2*2*1024*sizeof(unsigned long long), stream);

    // fused gather + xW GEMM, both directions in one dispatch
    gemm_emb_k<<<dim3(NTOK/128, G4/64, 2), 256, 0, stream>>>(tokens, word_emb,
                                                             w_ih_f, w_ih_b, xwf, xwb,
                                                             b_ih_f, b_hh_f, b_ih_b, b_hh_b);

    {
        const float *p_xwf = xwf, *p_xwb = xwb, *p_whf = w_hh_f, *p_whb = w_hh_b;
        unsigned long long* p_ht = hteam;
        float *p_hf = hf_all, *p_hb = hb_all;
        const unsigned* p_lc = lcnt;
        void* args[8] = {&p_xwf, &p_xwb, &p_whf, &p_whb, &p_ht, &p_hf, &p_hb, &p_lc};
        hipLaunchCooperativeKernel(lstm_k, dim3(256), dim3(256), args, 0u, stream);
    }

    combine_k<<<(NTOK*144 + 255)/256, 256, 0, stream>>>(hf_all, hb_all, bio_gold, bio_emb, oc);

    gemm_k<64><<<dim3(NTOK/64, 1), 256, 0, stream>>>(oc, OCD, emission_w, HD, emi, NT, NT, HD, emission_b, nullptr, 0);
    gemm_dual_k<64><<<dim3(NTOK/64, 2, 2), 256, 0, stream>>>(oc, oc, OCD, sel_u_w, sel_v_w, OCD,
                                                             u_, v_, RE, RE, OCD, sel_u_b, sel_v_b, 1);
    gemm_dual_k<64><<<dim3(NTOK/64, 2, 2), 256, 0, stream>>>(u_, v_, RE, sel_uv_w, sel_uv_w + RE, 2*RE,
                                                             U2, V2, RE, RE, RE, nullptr, nullptr, 0);

    crf_k<<<NB, 64, 0, stream>>>(emi, bio_gold, tokens, crf_trans, crf_start, crf_end, accum + 0, accum + 2);
    sel_k<<<dim3(2, SL, NB), 256, 0, stream>>>(U2, V2, sel_uv_b, rel_emb, sel_gold, tokens, accum + 1);

    finalize_k<<<1, 1, 0, stream>>>(accum, (float*)d_out, lcnt);
}

// Round 3
// 1434.545 us; speedup vs baseline: 3.3269x; 3.3269x over previous
//
#include <hip/hip_runtime.h>
#include <math.h>

// Problem dims
#define NB   16     // batch
#define SL   128    // seq len
#define ED   300    // word emb dim
#define HD   512    // lstm hidden
#define G4   2048   // 4*HD
#define NT   9      // tag count T
#define BE   64     // bio emb dim
#define RE   128    // REL_E
#define NR   50     // R
#define OCD  576    // HD + BE
#define NTOK 2048   // NB*SL

__device__ __forceinline__ float sigf(float x){ return 1.0f/(1.0f + __expf(-x)); }

// ---------------------------------------------------------------- generic fp32 GEMM body
template<int TM>
__device__ __forceinline__ void gemm_body(const float* __restrict__ A, int lda,
                                          const float* __restrict__ Bm, int ldb,
                                          float* __restrict__ C, int ldc,
                                          int N, int K,
                                          const float* __restrict__ bias1,
                                          const float* __restrict__ bias2,
                                          int do_relu, int m_blk, int n_blk)
{
    constexpr int TR = TM/16;
    __shared__ float As[16][TM+4];
    __shared__ float Bs[16][68];
    const int t = threadIdx.x;
    const int tm = (t >> 4) * TR;
    const int tn = (t & 15) * 4;
    float acc[TR][4];
    #pragma unroll
    for (int i=0;i<TR;++i){ acc[i][0]=0.f; acc[i][1]=0.f; acc[i][2]=0.f; acc[i][3]=0.f; }

    const int kc = (K + 15) >> 4;
    for (int ck = 0; ck < kc; ++ck){
        const int k0 = ck << 4;
        __syncthreads();
        #pragma unroll
        for (int it = 0; it < TM/64; ++it){
            int task = t + it*256;
            int m = task >> 2, q = task & 3;
            int kk = k0 + q*4;
            float4 v = make_float4(0.f,0.f,0.f,0.f);
            const float* ap = A + (size_t)(m_blk + m)*lda + kk;
            if (kk + 3 < K) v = *(const float4*)ap;
            else {
                if (kk   < K) v.x = ap[0];
                if (kk+1 < K) v.y = ap[1];
                if (kk+2 < K) v.z = ap[2];
            }
            As[q*4+0][m] = v.x; As[q*4+1][m] = v.y; As[q*4+2][m] = v.z; As[q*4+3][m] = v.w;
        }
        {
            int n = t >> 2, q = t & 3;
            int kk = k0 + q*4;
            int gn = n_blk + n;
            float4 v = make_float4(0.f,0.f,0.f,0.f);
            if (gn < N){
                const float* bp = Bm + (size_t)gn*ldb + kk;
                if (kk + 3 < K) v = *(const float4*)bp;
                else {
                    if (kk   < K) v.x = bp[0];
                    if (kk+1 < K) v.y = bp[1];
                    if (kk+2 < K) v.z = bp[2];
                }
            }
            Bs[q*4+0][n] = v.x; Bs[q*4+1][n] = v.y; Bs[q*4+2][n] = v.z; Bs[q*4+3][n] = v.w;
        }
        __syncthreads();
        #pragma unroll
        for (int k = 0; k < 16; ++k){
            float4 b4 = *(const float4*)&Bs[k][tn];
            float bn[4] = {b4.x, b4.y, b4.z, b4.w};
            #pragma unroll
            for (int i = 0; i < TR/4; ++i){
                float4 a4 = *(const float4*)&As[k][tm + i*4];
                float am[4] = {a4.x, a4.y, a4.z, a4.w};
                #pragma unroll
                for (int mm = 0; mm < 4; ++mm){
                    #pragma unroll
                    for (int nn = 0; nn < 4; ++nn)
                        acc[i*4+mm][nn] += am[mm]*bn[nn];
                }
            }
        }
    }
    float bv[4];
    #pragma unroll
    for (int nn=0;nn<4;++nn){
        int gn = n_blk + tn + nn;
        float bb = 0.f;
        if (gn < N){
            if (bias1) bb += bias1[gn];
            if (bias2) bb += bias2[gn];
        }
        bv[nn] = bb;
    }
    bool vec = ((ldc & 3) == 0) && (n_blk + tn + 3 < N);
    #pragma unroll
    for (int mm = 0; mm < TR; ++mm){
        int gm = m_blk + tm + mm;
        float r0 = acc[mm][0] + bv[0];
        float r1 = acc[mm][1] + bv[1];
        float r2 = acc[mm][2] + bv[2];
        float r3 = acc[mm][3] + bv[3];
        if (do_relu){ r0=fmaxf(r0,0.f); r1=fmaxf(r1,0.f); r2=fmaxf(r2,0.f); r3=fmaxf(r3,0.f); }
        if (vec){
            *(float4*)(C + (size_t)gm*ldc + n_blk + tn) = make_float4(r0,r1,r2,r3);
        } else {
            int gn = n_blk + tn;
            if (gn   < N) C[(size_t)gm*ldc + gn  ] = r0;
            if (gn+1 < N) C[(size_t)gm*ldc + gn+1] = r1;
            if (gn+2 < N) C[(size_t)gm*ldc + gn+2] = r2;
            if (gn+3 < N) C[(size_t)gm*ldc + gn+3] = r3;
        }
    }
}

template<int TM>
__global__ __launch_bounds__(256) void gemm_k(const float* __restrict__ A, int lda,
                                              const float* __restrict__ Bm, int ldb,
                                              float* __restrict__ C, int ldc,
                                              int N, int K,
                                              const float* __restrict__ bias1,
                                              const float* __restrict__ bias2,
                                              int do_relu)
{
    gemm_body<TM>(A, lda, Bm, ldb, C, ldc, N, K, bias1, bias2, do_relu,
                  blockIdx.x * TM, blockIdx.y * 64);
}

template<int TM>
__global__ __launch_bounds__(256) void gemm_dual_k(const float* __restrict__ A0, const float* __restrict__ A1, int lda,
                                                   const float* __restrict__ B0, const float* __restrict__ B1, int ldb,
                                                   float* __restrict__ C0, float* __restrict__ C1, int ldc,
                                                   int N, int K,
                                                   const float* __restrict__ bias0, const float* __restrict__ bias1,
                                                   int do_relu)
{
    const int z = blockIdx.z;
    gemm_body<TM>(z ? A1 : A0, lda, z ? B1 : B0, ldb, z ? C1 : C0, ldc, N, K,
                  z ? bias1 : bias0, nullptr, do_relu, blockIdx.x * TM, blockIdx.y * 64);
}

// ---------------------------------------------------------------- xW GEMM with fused token-gather
__global__ __launch_bounds__(256) void gemm_emb_k(const int* __restrict__ tokens,
                                                  const float* __restrict__ word_emb,
                                                  const float* __restrict__ B0, const float* __restrict__ B1,
                                                  float* __restrict__ C0, float* __restrict__ C1,
                                                  const float* __restrict__ bi0a, const float* __restrict__ bi0b,
                                                  const float* __restrict__ bi1a, const float* __restrict__ bi1b)
{
    __shared__ float As[16][132];
    __shared__ float Bs[16][68];
    const int z = blockIdx.z;
    const float* Bm = z ? B1 : B0;
    float* C       = z ? C1 : C0;
    const float* ba = z ? bi1a : bi0a;
    const float* bb = z ? bi1b : bi0b;
    const int t = threadIdx.x;
    const int m_blk = blockIdx.x * 128;
    const int n_blk = blockIdx.y * 64;
    const int tm = (t >> 4) * 8;
    const int tn = (t & 15) * 4;
    float acc[8][4];
    #pragma unroll
    for (int i=0;i<8;++i){ acc[i][0]=0.f; acc[i][1]=0.f; acc[i][2]=0.f; acc[i][3]=0.f; }

    for (int ck = 0; ck < 19; ++ck){
        const int k0 = ck << 4;
        __syncthreads();
        #pragma unroll
        for (int it = 0; it < 2; ++it){
            int task = t + it*256;
            int m = task >> 2, q = task & 3;
            int kk = k0 + q*4;
            const int tok = tokens[m_blk + m];
            const float* ap = word_emb + (size_t)tok*ED + kk;
            float4 v = make_float4(0.f,0.f,0.f,0.f);
            if (kk + 3 < ED) v = *(const float4*)ap;
            else {
                if (kk   < ED) v.x = ap[0];
                if (kk+1 < ED) v.y = ap[1];
                if (kk+2 < ED) v.z = ap[2];
            }
            As[q*4+0][m] = v.x; As[q*4+1][m] = v.y; As[q*4+2][m] = v.z; As[q*4+3][m] = v.w;
        }
        {
            int n = t >> 2, q = t & 3;
            int kk = k0 + q*4;
            const float* bp = Bm + (size_t)(n_blk + n)*ED + kk;
            float4 v = make_float4(0.f,0.f,0.f,0.f);
            if (kk + 3 < ED) v = *(const float4*)bp;
            else {
                if (kk   < ED) v.x = bp[0];
                if (kk+1 < ED) v.y = bp[1];
                if (kk+2 < ED) v.z = bp[2];
            }
            Bs[q*4+0][n] = v.x; Bs[q*4+1][n] = v.y; Bs[q*4+2][n] = v.z; Bs[q*4+3][n] = v.w;
        }
        __syncthreads();
        #pragma unroll
        for (int k = 0; k < 16; ++k){
            float4 b4 = *(const float4*)&Bs[k][tn];
            float bn[4] = {b4.x, b4.y, b4.z, b4.w};
            #pragma unroll
            for (int i = 0; i < 2; ++i){
                float4 a4 = *(const float4*)&As[k][tm + i*4];
                float am[4] = {a4.x, a4.y, a4.z, a4.w};
                #pragma unroll
                for (int mm = 0; mm < 4; ++mm){
                    #pragma unroll
                    for (int nn = 0; nn < 4; ++nn)
                        acc[i*4+mm][nn] += am[mm]*bn[nn];
                }
            }
        }
    }
    float bv[4];
    #pragma unroll
    for (int nn=0;nn<4;++nn){ int gn = n_blk + tn + nn; bv[nn] = ba[gn] + bb[gn]; }
    #pragma unroll
    for (int mm = 0; mm < 8; ++mm){
        int gm = m_blk + tm + mm;
        *(float4*)(C + (size_t)gm*G4 + n_blk + tn) =
            make_float4(acc[mm][0]+bv[0], acc[mm][1]+bv[1], acc[mm][2]+bv[2], acc[mm][3]+bv[3]);
    }
}

// ---------------------------------------------------------------- LSTM exchange helpers (agent scope, via IC)
__device__ __forceinline__ unsigned long long agld(const unsigned long long* p){
    return __hip_atomic_load(p, __ATOMIC_RELAXED, __HIP_MEMORY_SCOPE_AGENT);
}
__device__ __forceinline__ void agst(unsigned long long* p, unsigned long long v){
    __hip_atomic_store(p, v, __ATOMIC_RELAXED, __HIP_MEMORY_SCOPE_AGENT);
}
__device__ __forceinline__ bool tagok(unsigned long long a, unsigned long long b,
                                      unsigned long long c, unsigned long long d, unsigned w){
    return ((unsigned)(a>>32)==w) & ((unsigned)(b>>32)==w) &
           ((unsigned)(c>>32)==w) & ((unsigned)(d>>32)==w);
}

// ---------------------------------------------------------------- 4-chain interleaved LSTM
// 4 teams x 32 wgs = 128 wgs. Each team owns 4 batches (2 pairs); each wg
// (rank) owns hidden [rank*16,+16) for BOTH dirs and BOTH pairs = 4
// independent recurrent chains: {pair0-fwd, pair0-bwd, pair1-fwd, pair1-bwd}.
// hh-weights are batch-independent, so the 256 weight VGPRs are shared by
// the two pairs. Per step the chains run round-robin: each chain's poll
// loads are issued one compute-phase (~1.5k cyc) early, and its h store has
// THREE compute phases (~3.6k cyc) before the next-step poll — covering the
// IC store->visible->load round trip that was the baseline's exposed wait
// (2 chains gave only ~1.2k cyc of cover; rocprof: VALUBusy 33%, 10k cyc/step).
// Exchange mechanism identical to the proven baseline: packed u64
// (tag<<32|float_bits), relaxed agent atomics, parity double-buffer,
// memset-0 provides step-0 tags.
__global__ __launch_bounds__(256, 1) void lstm_k(const float* __restrict__ xwf,
                                                 const float* __restrict__ xwb,
                                                 const float* __restrict__ whhf,
                                                 const float* __restrict__ whhb,
                                                 unsigned long long* __restrict__ hteam, // 4 teams*4 chains*2 par*1024 u64
                                                 float* __restrict__ hf_all,
                                                 float* __restrict__ hb_all)
{
    __shared__ __align__(16) float h_s[4][2*HD];   // 16 KB staging, one buf per chain
    __shared__ __align__(16) float part[8*128];    // 4 KB [kc][row*2+b]
    __shared__ float gates_s[128];                 // [row*2+b]
    __shared__ float cst[4*32];                    // [chain][hid*2+b]
    const int wg   = blockIdx.x;
    const int team = wg >> 5;                      // 0..3
    const int rank = wg & 31;
    const int b0   = team * 4;                     // 4 batches per team
    const int t    = threadIdx.x;
    const int wv   = t >> 6;
    const int lane = t & 63;
    const int rg   = t & 31;
    const int kc   = t >> 5;                       // 0..7 (64 k each)
    const int lr0  = rg*2, lr1 = rg*2 + 1;
    const int grow0 = (lr0 >> 4)*HD + rank*16 + (lr0 & 15);
    const int grow1 = (lr1 >> 4)*HD + rank*16 + (lr1 & 15);
    unsigned long long* hT0 = hteam + (size_t)((team*4 + 0)*2)*1024;
    unsigned long long* hT1 = hteam + (size_t)((team*4 + 1)*2)*1024;
    unsigned long long* hT2 = hteam + (size_t)((team*4 + 2)*2)*1024;
    unsigned long long* hT3 = hteam + (size_t)((team*4 + 3)*2)*1024;

    // ---- one-time: both dirs' weight slices into registers (64 float4 = 256 VGPRs) ----
    float4 wf0[16], wf1[16], wb0[16], wb1[16];
    {
        const float* p0 = whhf + (size_t)grow0*HD + kc*64;
        const float* p1 = whhf + (size_t)grow1*HD + kc*64;
        const float* p2 = whhb + (size_t)grow0*HD + kc*64;
        const float* p3 = whhb + (size_t)grow1*HD + kc*64;
        #pragma unroll
        for (int q = 0; q < 16; ++q){
            wf0[q] = *(const float4*)(p0 + q*4);
            wf1[q] = *(const float4*)(p1 + q*4);
            wb0[q] = *(const float4*)(p2 + q*4);
            wb1[q] = *(const float4*)(p3 + q*4);
        }
    }
    // reduce mapping (t<128): entry = row*2 + b
    const int rrow = t >> 1, rb2 = t & 1;
    const int growr = (rrow >> 4)*HD + rank*16 + (rrow & 15);
    // activation mapping (t<32)
    const int ahl = t >> 1, ab2 = t & 1;
    const int hidx_a = rank*16 + ahl;
    // staging slots (4 u64/thread/chain): b in {0,1}, halves {0,64}
    const int s0 = wv*128 + lane;

    if (t < 128) cst[t] = 0.f;
    __syncthreads();

    // prologue: prefetch chain0 par0 (step-0 tags come from memset 0)
    unsigned long long c0a, c0b, c0c, c0d;
    {
        const unsigned long long* src = hT0;
        c0a = agld(&src[s0]); c0b = agld(&src[s0+64]);
        c0c = agld(&src[512+s0]); c0d = agld(&src[512+s0+64]);
    }

    int par = 0;
    for (int s = 0; s < SL; ++s){
        const unsigned want = (unsigned)s;
        const unsigned long long tag1 = ((unsigned long long)(unsigned)(s+1)) << 32;
        float xv0 = 0.f, xv1 = 0.f, xv2 = 0.f, xv3 = 0.f;
        if (t < 128){
            xv0 = xwf[(size_t)((b0     + rb2)*SL + s       )*G4 + growr];
            xv1 = xwb[(size_t)((b0     + rb2)*SL + (SL-1-s))*G4 + growr];
            xv2 = xwf[(size_t)((b0 + 2 + rb2)*SL + s       )*G4 + growr];
            xv3 = xwb[(size_t)((b0 + 2 + rb2)*SL + (SL-1-s))*G4 + growr];
        }

        // ================= chain 0: pair0 fwd =================
        if (!tagok(c0a,c0b,c0c,c0d,want)){
            const unsigned long long* src = hT0 + (size_t)par*1024;
            for (;;){
                c0a = agld(&src[s0]); c0b = agld(&src[s0+64]);
                c0c = agld(&src[512+s0]); c0d = agld(&src[512+s0+64]);
                if (tagok(c0a,c0b,c0c,c0d,want)) break;
                __builtin_amdgcn_s_sleep(1);
            }
        }
        h_s[0][     s0     ] = __uint_as_float((unsigned)c0a);
        h_s[0][     s0 + 64] = __uint_as_float((unsigned)c0b);
        h_s[0][HD + s0     ] = __uint_as_float((unsigned)c0c);
        h_s[0][HD + s0 + 64] = __uint_as_float((unsigned)c0d);
        // issue chain1 poll loads (in flight during chain0 compute)
        unsigned long long c1a, c1b, c1c, c1d;
        {
            const unsigned long long* src = hT1 + (size_t)par*1024;
            c1a = agld(&src[s0]); c1b = agld(&src[s0+64]);
            c1c = agld(&src[512+s0]); c1d = agld(&src[512+s0+64]);
        }
        {
            float a00=0.f,a01=0.f,a10=0.f,a11=0.f;
            #pragma unroll
            for (int q = 0; q < 16; ++q){
                float4 wa = wf0[q], wb = wf1[q];
                float4 h0 = *(const float4*)(&h_s[0][0]  + kc*64 + q*4);
                float4 h1 = *(const float4*)(&h_s[0][HD] + kc*64 + q*4);
                a00 += wa.x*h0.x + wa.y*h0.y + wa.z*h0.z + wa.w*h0.w;
                a01 += wa.x*h1.x + wa.y*h1.y + wa.z*h1.z + wa.w*h1.w;
                a10 += wb.x*h0.x + wb.y*h0.y + wb.z*h0.z + wb.w*h0.w;
                a11 += wb.x*h1.x + wb.y*h1.y + wb.z*h1.z + wb.w*h1.w;
            }
            *(float4*)&part[kc*128 + lr0*2] = make_float4(a00,a01,a10,a11);
        }
        __syncthreads();
        if (t < 128){
            float g = 0.f;
            #pragma unroll
            for (int c = 0; c < 8; ++c) g += part[c*128 + t];
            gates_s[t] = g + xv0;
        }
        __syncthreads();
        if (t < 32){
            float gi = gates_s[(0*16 + ahl)*2 + ab2];
            float gf = gates_s[(1*16 + ahl)*2 + ab2];
            float gc = gates_s[(2*16 + ahl)*2 + ab2];
            float go_ = gates_s[(3*16 + ahl)*2 + ab2];
            float cp = cst[t];
            float cn = sigf(gf)*cp + sigf(gi)*tanhf(gc);
            float hn = sigf(go_)*tanhf(cn);
            cst[t] = cn;
            agst(&hT0[(size_t)(par^1)*1024 + ab2*512 + hidx_a],
                 tag1 | (unsigned long long)__float_as_uint(hn));
            hf_all[(size_t)((b0 + ab2)*SL + s)*HD + hidx_a] = hn;
        }

        // ================= chain 1: pair0 bwd =================
        if (!tagok(c1a,c1b,c1c,c1d,want)){
            const unsigned long long* src = hT1 + (size_t)par*1024;
            for (;;){
                c1a = agld(&src[s0]); c1b = agld(&src[s0+64]);
                c1c = agld(&src[512+s0]); c1d = agld(&src[512+s0+64]);
                if (tagok(c1a,c1b,c1c,c1d,want)) break;
                __builtin_amdgcn_s_sleep(1);
            }
        }
        h_s[1][     s0     ] = __uint_as_float((unsigned)c1a);
        h_s[1][     s0 + 64] = __uint_as_float((unsigned)c1b);
        h_s[1][HD + s0     ] = __uint_as_float((unsigned)c1c);
        h_s[1][HD + s0 + 64] = __uint_as_float((unsigned)c1d);
        // issue chain2 poll loads
        unsigned long long c2a, c2b, c2c, c2d;
        {
            const unsigned long long* src = hT2 + (size_t)par*1024;
            c2a = agld(&src[s0]); c2b = agld(&src[s0+64]);
            c2c = agld(&src[512+s0]); c2d = agld(&src[512+s0+64]);
        }
        {
            float a00=0.f,a01=0.f,a10=0.f,a11=0.f;
            #pragma unroll
            for (int q = 0; q < 16; ++q){
                float4 wa = wb0[q], wb = wb1[q];
                float4 h0 = *(const float4*)(&h_s[1][0]  + kc*64 + q*4);
                float4 h1 = *(const float4*)(&h_s[1][HD] + kc*64 + q*4);
                a00 += wa.x*h0.x + wa.y*h0.y + wa.z*h0.z + wa.w*h0.w;
                a01 += wa.x*h1.x + wa.y*h1.y + wa.z*h1.z + wa.w*h1.w;
                a10 += wb.x*h0.x + wb.y*h0.y + wb.z*h0.z + wb.w*h0.w;
                a11 += wb.x*h1.x + wb.y*h1.y + wb.z*h1.z + wb.w*h1.w;
            }
            *(float4*)&part[kc*128 + lr0*2] = make_float4(a00,a01,a10,a11);
        }
        __syncthreads();
        if (t < 128){
            float g = 0.f;
            #pragma unroll
            for (int c = 0; c < 8; ++c) g += part[c*128 + t];
            gates_s[t] = g + xv1;
        }
        __syncthreads();
        if (t < 32){
            float gi = gates_s[(0*16 + ahl)*2 + ab2];
            float gf = gates_s[(1*16 + ahl)*2 + ab2];
            float gc = gates_s[(2*16 + ahl)*2 + ab2];
            float go_ = gates_s[(3*16 + ahl)*2 + ab2];
            float cp = cst[32 + t];
            float cn = sigf(gf)*cp + sigf(gi)*tanhf(gc);
            float hn = sigf(go_)*tanhf(cn);
            cst[32 + t] = cn;
            agst(&hT1[(size_t)(par^1)*1024 + ab2*512 + hidx_a],
                 tag1 | (unsigned long long)__float_as_uint(hn));
            hb_all[(size_t)((b0 + ab2)*SL + (SL-1 - s))*HD + hidx_a] = hn;
        }

        // ================= chain 2: pair1 fwd =================
        if (!tagok(c2a,c2b,c2c,c2d,want)){
            const unsigned long long* src = hT2 + (size_t)par*1024;
            for (;;){
                c2a = agld(&src[s0]); c2b = agld(&src[s0+64]);
                c2c = agld(&src[512+s0]); c2d = agld(&src[512+s0+64]);
                if (tagok(c2a,c2b,c2c,c2d,want)) break;
                __builtin_amdgcn_s_sleep(1);
            }
        }
        h_s[2][     s0     ] = __uint_as_float((unsigned)c2a);
        h_s[2][     s0 + 64] = __uint_as_float((unsigned)c2b);
        h_s[2][HD + s0     ] = __uint_as_float((unsigned)c2c);
        h_s[2][HD + s0 + 64] = __uint_as_float((unsigned)c2d);
        // issue chain3 poll loads
        unsigned long long c3a, c3b, c3c, c3d;
        {
            const unsigned long long* src = hT3 + (size_t)par*1024;
            c3a = agld(&src[s0]); c3b = agld(&src[s0+64]);
            c3c = agld(&src[512+s0]); c3d = agld(&src[512+s0+64]);
        }
        {
            float a00=0.f,a01=0.f,a10=0.f,a11=0.f;
            #pragma unroll
            for (int q = 0; q < 16; ++q){
                float4 wa = wf0[q], wb = wf1[q];
                float4 h0 = *(const float4*)(&h_s[2][0]  + kc*64 + q*4);
                float4 h1 = *(const float4*)(&h_s[2][HD] + kc*64 + q*4);
                a00 += wa.x*h0.x + wa.y*h0.y + wa.z*h0.z + wa.w*h0.w;
                a01 += wa.x*h1.x + wa.y*h1.y + wa.z*h1.z + wa.w*h1.w;
                a10 += wb.x*h0.x + wb.y*h0.y + wb.z*h0.z + wb.w*h0.w;
                a11 += wb.x*h1.x + wb.y*h1.y + wb.z*h1.z + wb.w*h1.w;
            }
            *(float4*)&part[kc*128 + lr0*2] = make_float4(a00,a01,a10,a11);
        }
        __syncthreads();
        if (t < 128){
            float g = 0.f;
            #pragma unroll
            for (int c = 0; c < 8; ++c) g += part[c*128 + t];
            gates_s[t] = g + xv2;
        }
        __syncthreads();
        if (t < 32){
            float gi = gates_s[(0*16 + ahl)*2 + ab2];
            float gf = gates_s[(1*16 + ahl)*2 + ab2];
            float gc = gates_s[(2*16 + ahl)*2 + ab2];
            float go_ = gates_s[(3*16 + ahl)*2 + ab2];
            float cp = cst[64 + t];
            float cn = sigf(gf)*cp + sigf(gi)*tanhf(gc);
            float hn = sigf(go_)*tanhf(cn);
            cst[64 + t] = cn;
            agst(&hT2[(size_t)(par^1)*1024 + ab2*512 + hidx_a],
                 tag1 | (unsigned long long)__float_as_uint(hn));
            hf_all[(size_t)((b0 + 2 + ab2)*SL + s)*HD + hidx_a] = hn;
        }

        // ================= chain 3: pair1 bwd =================
        if (!tagok(c3a,c3b,c3c,c3d,want)){
            const unsigned long long* src = hT3 + (size_t)par*1024;
            for (;;){
                c3a = agld(&src[s0]); c3b = agld(&src[s0+64]);
                c3c = agld(&src[512+s0]); c3d = agld(&src[512+s0+64]);
                if (tagok(c3a,c3b,c3c,c3d,want)) break;
                __builtin_amdgcn_s_sleep(1);
            }
        }
        h_s[3][     s0     ] = __uint_as_float((unsigned)c3a);
        h_s[3][     s0 + 64] = __uint_as_float((unsigned)c3b);
        h_s[3][HD + s0     ] = __uint_as_float((unsigned)c3c);
        h_s[3][HD + s0 + 64] = __uint_as_float((unsigned)c3d);
        // prefetch chain0 for NEXT step (its data was stored early this step)
        {
            const unsigned long long* src = hT0 + (size_t)(par^1)*1024;
            c0a = agld(&src[s0]); c0b = agld(&src[s0+64]);
            c0c = agld(&src[512+s0]); c0d = agld(&src[512+s0+64]);
        }
        {
            float a00=0.f,a01=0.f,a10=0.f,a11=0.f;
            #pragma unroll
            for (int q = 0; q < 16; ++q){
                float4 wa = wb0[q], wb = wb1[q];
                float4 h0 = *(const float4*)(&h_s[3][0]  + kc*64 + q*4);
                float4 h1 = *(const float4*)(&h_s[3][HD] + kc*64 + q*4);
                a00 += wa.x*h0.x + wa.y*h0.y + wa.z*h0.z + wa.w*h0.w;
                a01 += wa.x*h1.x + wa.y*h1.y + wa.z*h1.z + wa.w*h1.w;
                a10 += wb.x*h0.x + wb.y*h0.y + wb.z*h0.z + wb.w*h0.w;
                a11 += wb.x*h1.x + wb.y*h1.y + wb.z*h1.z + wb.w*h1.w;
            }
            *(float4*)&part[kc*128 + lr0*2] = make_float4(a00,a01,a10,a11);
        }
        __syncthreads();
        if (t < 128){
            float g = 0.f;
            #pragma unroll
            for (int c = 0; c < 8; ++c) g += part[c*128 + t];
            gates_s[t] = g + xv3;
        }
        __syncthreads();
        if (t < 32){
            float gi = gates_s[(0*16 + ahl)*2 + ab2];
            float gf = gates_s[(1*16 + ahl)*2 + ab2];
            float gc = gates_s[(2*16 + ahl)*2 + ab2];
            float go_ = gates_s[(3*16 + ahl)*2 + ab2];
            float cp = cst[96 + t];
            float cn = sigf(gf)*cp + sigf(gi)*tanhf(gc);
            float hn = sigf(go_)*tanhf(cn);
            cst[96 + t] = cn;
            agst(&hT3[(size_t)(par^1)*1024 + ab2*512 + hidx_a],
                 tag1 | (unsigned long long)__float_as_uint(hn));
            hb_all[(size_t)((b0 + 2 + ab2)*SL + (SL-1 - s))*HD + hidx_a] = hn;
        }
        par ^= 1;
    }
}

// ---------------------------------------------------------------- combine o | bio_emb
__global__ __launch_bounds__(256) void combine_k(const float* __restrict__ hf,
                                                 const float* __restrict__ hb,
                                                 const int* __restrict__ bio_gold,
                                                 const float* __restrict__ bio_emb,
                                                 float* __restrict__ oc)
{
    int idx = blockIdx.x*256 + threadIdx.x;
    if (idx >= NTOK*144) return;
    int row = idx / 144;
    int c4 = (idx - row*144) * 4;
    float4 v;
    if (c4 < HD){
        float4 a = *(const float4*)(hf + (size_t)row*HD + c4);
        float4 b = *(const float4*)(hb + (size_t)row*HD + c4);
        v = make_float4(0.5f*(a.x+b.x), 0.5f*(a.y+b.y), 0.5f*(a.z+b.z), 0.5f*(a.w+b.w));
    } else {
        int bg = bio_gold[row];
        v = *(const float4*)(bio_emb + bg*BE + (c4 - HD));
    }
    *(float4*)(oc + (size_t)row*OCD + c4) = v;
}

// ---------------------------------------------------------------- CRF NLL (wave-sync) + msum
__global__ __launch_bounds__(64) void crf_k(const float* __restrict__ emi,
                                            const int* __restrict__ tags,
                                            const int* __restrict__ tokens,
                                            const float* __restrict__ trans,
                                            const float* __restrict__ startv,
                                            const float* __restrict__ endv,
                                            float* __restrict__ out_crf,
                                            float* __restrict__ out_m)
{
    const int b = blockIdx.x, lane = threadIdx.x;
    unsigned long long m0 = __ballot(tokens[b*SL + lane] != 0);
    unsigned long long m1 = __ballot(tokens[b*SL + 64 + lane] != 0);
    const int len = __popcll(m0) + __popcll(m1);
    float npart = 0.f;
    #pragma unroll
    for (int half = 0; half < 2; ++half){
        int tt = lane + half*64;
        if (tt >= 1 && tt < len){
            int tp = tags[b*SL + tt - 1], tc = tags[b*SL + tt];
            npart += trans[tp*NT + tc] + emi[(size_t)(b*SL + tt)*NT + tc];
        }
    }
    #pragma unroll
    for (int off = 32; off > 0; off >>= 1) npart += __shfl_down(npart, off);
    float tr[NT]; float alpha = -1e30f;
    if (lane < NT){
        #pragma unroll
        for (int i = 0; i < NT; ++i) tr[i] = trans[i*NT + lane];
        alpha = startv[lane] + emi[(size_t)(b*SL)*NT + lane];
    }
    for (int tt = 1; tt < SL; ++tt){
        float al[NT];
        #pragma unroll
        for (int i = 0; i < NT; ++i) al[i] = __shfl(alpha, i);
        if (lane < NT && tt < len){
            float mx = -1e30f;
            #pragma unroll
            for (int i = 0; i < NT; ++i) mx = fmaxf(mx, al[i] + tr[i]);
            float se = 0.f;
            #pragma unroll
            for (int i = 0; i < NT; ++i) se += __expf(al[i] + tr[i] - mx);
            alpha = mx + __logf(se) + emi[(size_t)(b*SL + tt)*NT + lane];
        }
    }
    float alf = (lane < NT) ? (alpha + endv[lane]) : -1e30f;
    float alE[NT];
    #pragma unroll
    for (int i = 0; i < NT; ++i) alE[i] = __shfl(alf, i);
    if (lane == 0){
        float mx = -1e30f;
        #pragma unroll
        for (int i = 0; i < NT; ++i) mx = fmaxf(mx, alE[i]);
        float se = 0.f;
        #pragma unroll
        for (int i = 0; i < NT; ++i) se += __expf(alE[i] - mx);
        float den = mx + __logf(se);
        int t0g = tags[b*SL];
        float num = startv[t0g] + emi[(size_t)(b*SL)*NT + t0g] + npart;
        num += endv[tags[b*SL + len - 1]];
        atomicAdd(out_crf, -(num - den) * (1.0f/16.0f));
        atomicAdd(out_m, (float)len);
    }
}

// ---------------------------------------------------------------- fused uv->logits->BCE
__global__ __launch_bounds__(256) void sel_k(const float* __restrict__ U2,
                                             const float* __restrict__ V2,
                                             const float* __restrict__ uvb,
                                             const float* __restrict__ rel_emb,
                                             const int* __restrict__ gold,
                                             const int* __restrict__ tokens,
                                             float* __restrict__ out_sel)
{
    __shared__ float ret_s[RE][52];
    __shared__ float pt_s[RE][68];
    __shared__ float vb_s[RE];
    __shared__ float mk_s[64];
    __shared__ float red_s[4];
    const int jt = blockIdx.x, qi = blockIdx.y, b = blockIdx.z;
    const int t = threadIdx.x;
    if (tokens[b*SL + qi] == 0) return;
    if (t < 32){
        float4 v4 = *(const float4*)(V2 + (size_t)(b*SL + qi)*RE + t*4);
        float4 b4 = *(const float4*)(uvb + t*4);
        vb_s[t*4+0] = v4.x + b4.x; vb_s[t*4+1] = v4.y + b4.y;
        vb_s[t*4+2] = v4.z + b4.z; vb_s[t*4+3] = v4.w + b4.w;
    }
    if (t < 64) mk_s[t] = (tokens[b*SL + jt*64 + t] != 0) ? 1.f : 0.f;
    {
        int r = t & 63;
        for (int q = t >> 6; q < 32; q += 4){
            if (r < NR){
                float4 e4 = *(const float4*)(rel_emb + (size_t)r*RE + q*4);
                ret_s[q*4+0][r] = e4.x; ret_s[q*4+1][r] = e4.y;
                ret_s[q*4+2][r] = e4.z; ret_s[q*4+3][r] = e4.w;
            } else if (r < 64){
                ret_s[q*4+0][r] = 0.f; ret_s[q*4+1][r] = 0.f;
                ret_s[q*4+2][r] = 0.f; ret_s[q*4+3][r] = 0.f;
            }
        }
    }
    __syncthreads();
    {
        int j = t & 63;
        for (int q = t >> 6; q < 32; q += 4){
            float4 u4 = *(const float4*)(U2 + (size_t)(b*SL + jt*64 + j)*RE + q*4);
            pt_s[q*4+0][j] = fmaxf(u4.x + vb_s[q*4+0], 0.f);
            pt_s[q*4+1][j] = fmaxf(u4.y + vb_s[q*4+1], 0.f);
            pt_s[q*4+2][j] = fmaxf(u4.z + vb_s[q*4+2], 0.f);
            pt_s[q*4+3][j] = fmaxf(u4.w + vb_s[q*4+3], 0.f);
        }
    }
    __syncthreads();
    const int mj = (t & 15) * 4;
    const int nr = (t >> 4) * 4;
    float accv[4][4];
    #pragma unroll
    for (int i=0;i<4;++i){ accv[i][0]=0.f; accv[i][1]=0.f; accv[i][2]=0.f; accv[i][3]=0.f; }
    #pragma unroll 4
    for (int k = 0; k < RE; ++k){
        float4 aj = *(const float4*)&pt_s[k][mj];
        float4 br = *(const float4*)&ret_s[k][nr];
        float am[4] = {aj.x, aj.y, aj.z, aj.w};
        float bn[4] = {br.x, br.y, br.z, br.w};
        #pragma unroll
        for (int mm = 0; mm < 4; ++mm){
            #pragma unroll
            for (int nn = 0; nn < 4; ++nn)
                accv[mm][nn] += am[mm]*bn[nn];
        }
    }
    float lsum = 0.f;
    #pragma unroll
    for (int nn = 0; nn < 4; ++nn){
        int r = nr + nn;
        if (r < NR){
            const int* gp = gold + (size_t)((b*SL + qi)*NR + r)*SL + jt*64 + mj;
            #pragma unroll
            for (int mm = 0; mm < 4; ++mm){
                float l = accv[mm][nn];
                float g = (float)gp[mm];
                float bce = fmaxf(l, 0.f) - l*g + __logf(1.f + __expf(-fabsf(l)));
                lsum += bce * mk_s[mj + mm];
            }
        }
    }
    #pragma unroll
    for (int off = 32; off > 0; off >>= 1) lsum += __shfl_down(lsum, off);
    if ((t & 63) == 0) red_s[t >> 6] = lsum;
    __syncthreads();
    if (t == 0) atomicAdd(out_sel, red_s[0]+red_s[1]+red_s[2]+red_s[3]);
}

// ---------------------------------------------------------------- finalize
__global__ void finalize_k(const float* __restrict__ accum, float* __restrict__ out)
{
    if (threadIdx.x == 0 && blockIdx.x == 0) out[0] = accum[0] + accum[1] / accum[2];
}

// ---------------------------------------------------------------- launch
extern "C" void kernel_launch(void* const* d_in, const int* in_sizes, int n_in,
                              void* d_out, int out_size, void* d_ws, size_t ws_size,
                              hipStream_t stream)
{
    const int*   tokens    = (const int*)  d_in[0];
    const int*   bio_gold  = (const int*)  d_in[1];
    const int*   sel_gold  = (const int*)  d_in[2];
    const float* word_emb  = (const float*)d_in[4];
    const float* rel_emb   = (const float*)d_in[5];
    const float* bio_emb   = (const float*)d_in[6];
    const float* w_ih_f    = (const float*)d_in[7];
    const float* w_hh_f    = (const float*)d_in[8];
    const float* b_ih_f    = (const float*)d_in[9];
    const float* b_hh_f    = (const float*)d_in[10];
    const float* w_ih_b    = (const float*)d_in[11];
    const float* w_hh_b    = (const float*)d_in[12];
    const float* b_ih_b    = (const float*)d_in[13];
    const float* b_hh_b    = (const float*)d_in[14];
    const float* emission_w= (const float*)d_in[15];
    const float* emission_b= (const float*)d_in[16];
    const float* sel_u_w   = (const float*)d_in[17];
    const float* sel_u_b   = (const float*)d_in[18];
    const float* sel_v_w   = (const float*)d_in[19];
    const float* sel_v_b   = (const float*)d_in[20];
    const float* sel_uv_w  = (const float*)d_in[21];
    const float* sel_uv_b  = (const float*)d_in[22];
    const float* crf_trans = (const float*)d_in[23];
    const float* crf_start = (const float*)d_in[24];
    const float* crf_end   = (const float*)d_in[25];
    (void)in_sizes; (void)n_in; (void)out_size; (void)ws_size;

    float* ws     = (float*)d_ws;
    float* emb    = ws;                         // region reused for hteam
    float* xwf    = emb    + (size_t)NTOK*ED;
    float* xwb    = xwf    + (size_t)NTOK*G4;
    float* hf_all = xwb    + (size_t)NTOK*G4;
    float* hb_all = hf_all + (size_t)NTOK*HD;
    float* oc     = hb_all + (size_t)NTOK*HD;
    float* emi    = oc     + (size_t)NTOK*OCD;
    float* u_     = emi    + (size_t)NTOK*NT;
    float* v_     = u_     + (size_t)NTOK*RE;
    float* U2     = v_     + (size_t)NTOK*RE;
    float* V2     = U2     + (size_t)NTOK*RE;
    float* accum  = V2     + (size_t)NTOK*RE;   // [0]=crf, [1]=sel_sum, [2]=msum, [3]=pad

    // packed h exchange: 4 teams x 4 chains x 2 parities x 1024 u64 = 256 KB
    unsigned long long* hteam = (unsigned long long*)emb;

    hipMemsetAsync(accum, 0, 4*sizeof(float), stream);
    hipMemsetAsync(hteam, 0, (size_t)4*4*2*1024*sizeof(unsigned long long), stream);

    // fused gather + xW GEMM, both directions in one dispatch
    gemm_emb_k<<<dim3(NTOK/128, G4/64, 2), 256, 0, stream>>>(tokens, word_emb,
                                                             w_ih_f, w_ih_b, xwf, xwb,
                                                             b_ih_f, b_hh_f, b_ih_b, b_hh_b);

    {
        const float *p_xwf = xwf, *p_xwb = xwb, *p_whf = w_hh_f, *p_whb = w_hh_b;
        unsigned long long* p_ht = hteam;
        float *p_hf = hf_all, *p_hb = hb_all;
        void* args[7] = {&p_xwf, &p_xwb, &p_whf, &p_whb, &p_ht, &p_hf, &p_hb};
        hipLaunchCooperativeKernel(lstm_k, dim3(128), dim3(256), args, 0u, stream);
    }

    combine_k<<<(NTOK*144 + 255)/256, 256, 0, stream>>>(hf_all, hb_all, bio_gold, bio_emb, oc);

    gemm_k<64><<<dim3(NTOK/64, 1), 256, 0, stream>>>(oc, OCD, emission_w, HD, emi, NT, NT, HD, emission_b, nullptr, 0);
    gemm_dual_k<64><<<dim3(NTOK/64, 2, 2), 256, 0, stream>>>(oc, oc, OCD, sel_u_w, sel_v_w, OCD,
                                                             u_, v_, RE, RE, OCD, sel_u_b, sel_v_b, 1);
    gemm_dual_k<64><<<dim3(NTOK/64, 2, 2), 256, 0, stream>>>(u_, v_, RE, sel_uv_w, sel_uv_w + RE, 2*RE,
                                                             U2, V2, RE, RE, RE, nullptr, nullptr, 0);

    crf_k<<<NB, 64, 0, stream>>>(emi, bio_gold, tokens, crf_trans, crf_start, crf_end, accum + 0, accum + 2);
    sel_k<<<dim3(2, SL, NB), 256, 0, stream>>>(U2, V2, sel_uv_b, rel_emb, sel_gold, tokens, accum + 1);

    finalize_k<<<1, 1, 0, stream>>>(accum, (float*)d_out);
}

// Round 4
// 865.349 us; speedup vs baseline: 5.5152x; 1.6578x over previous
//
#include <hip/hip_runtime.h>
#include <math.h>

// Problem dims
#define NB   16     // batch
#define SL   128    // seq len
#define ED   300    // word emb dim
#define HD   512    // lstm hidden
#define G4   2048   // 4*HD
#define NT   9      // tag count T
#define BE   64     // bio emb dim
#define RE   128    // REL_E
#define NR   50     // R
#define OCD  576    // HD + BE
#define NTOK 2048   // NB*SL

__device__ __forceinline__ float sigf(float x){ return 1.0f/(1.0f + __expf(-x)); }

// ---------------------------------------------------------------- generic fp32 GEMM body
template<int TM>
__device__ __forceinline__ void gemm_body(const float* __restrict__ A, int lda,
                                          const float* __restrict__ Bm, int ldb,
                                          float* __restrict__ C, int ldc,
                                          int N, int K,
                                          const float* __restrict__ bias1,
                                          const float* __restrict__ bias2,
                                          int do_relu, int m_blk, int n_blk)
{
    constexpr int TR = TM/16;
    __shared__ float As[16][TM+4];
    __shared__ float Bs[16][68];
    const int t = threadIdx.x;
    const int tm = (t >> 4) * TR;
    const int tn = (t & 15) * 4;
    float acc[TR][4];
    #pragma unroll
    for (int i=0;i<TR;++i){ acc[i][0]=0.f; acc[i][1]=0.f; acc[i][2]=0.f; acc[i][3]=0.f; }

    const int kc = (K + 15) >> 4;
    for (int ck = 0; ck < kc; ++ck){
        const int k0 = ck << 4;
        __syncthreads();
        #pragma unroll
        for (int it = 0; it < TM/64; ++it){
            int task = t + it*256;
            int m = task >> 2, q = task & 3;
            int kk = k0 + q*4;
            float4 v = make_float4(0.f,0.f,0.f,0.f);
            const float* ap = A + (size_t)(m_blk + m)*lda + kk;
            if (kk + 3 < K) v = *(const float4*)ap;
            else {
                if (kk   < K) v.x = ap[0];
                if (kk+1 < K) v.y = ap[1];
                if (kk+2 < K) v.z = ap[2];
            }
            As[q*4+0][m] = v.x; As[q*4+1][m] = v.y; As[q*4+2][m] = v.z; As[q*4+3][m] = v.w;
        }
        {
            int n = t >> 2, q = t & 3;
            int kk = k0 + q*4;
            int gn = n_blk + n;
            float4 v = make_float4(0.f,0.f,0.f,0.f);
            if (gn < N){
                const float* bp = Bm + (size_t)gn*ldb + kk;
                if (kk + 3 < K) v = *(const float4*)bp;
                else {
                    if (kk   < K) v.x = bp[0];
                    if (kk+1 < K) v.y = bp[1];
                    if (kk+2 < K) v.z = bp[2];
                }
            }
            Bs[q*4+0][n] = v.x; Bs[q*4+1][n] = v.y; Bs[q*4+2][n] = v.z; Bs[q*4+3][n] = v.w;
        }
        __syncthreads();
        #pragma unroll
        for (int k = 0; k < 16; ++k){
            float4 b4 = *(const float4*)&Bs[k][tn];
            float bn[4] = {b4.x, b4.y, b4.z, b4.w};
            #pragma unroll
            for (int i = 0; i < TR/4; ++i){
                float4 a4 = *(const float4*)&As[k][tm + i*4];
                float am[4] = {a4.x, a4.y, a4.z, a4.w};
                #pragma unroll
                for (int mm = 0; mm < 4; ++mm){
                    #pragma unroll
                    for (int nn = 0; nn < 4; ++nn)
                        acc[i*4+mm][nn] += am[mm]*bn[nn];
                }
            }
        }
    }
    float bv[4];
    #pragma unroll
    for (int nn=0;nn<4;++nn){
        int gn = n_blk + tn + nn;
        float bb = 0.f;
        if (gn < N){
            if (bias1) bb += bias1[gn];
            if (bias2) bb += bias2[gn];
        }
        bv[nn] = bb;
    }
    bool vec = ((ldc & 3) == 0) && (n_blk + tn + 3 < N);
    #pragma unroll
    for (int mm = 0; mm < TR; ++mm){
        int gm = m_blk + tm + mm;
        float r0 = acc[mm][0] + bv[0];
        float r1 = acc[mm][1] + bv[1];
        float r2 = acc[mm][2] + bv[2];
        float r3 = acc[mm][3] + bv[3];
        if (do_relu){ r0=fmaxf(r0,0.f); r1=fmaxf(r1,0.f); r2=fmaxf(r2,0.f); r3=fmaxf(r3,0.f); }
        if (vec){
            *(float4*)(C + (size_t)gm*ldc + n_blk + tn) = make_float4(r0,r1,r2,r3);
        } else {
            int gn = n_blk + tn;
            if (gn   < N) C[(size_t)gm*ldc + gn  ] = r0;
            if (gn+1 < N) C[(size_t)gm*ldc + gn+1] = r1;
            if (gn+2 < N) C[(size_t)gm*ldc + gn+2] = r2;
            if (gn+3 < N) C[(size_t)gm*ldc + gn+3] = r3;
        }
    }
}

template<int TM>
__global__ __launch_bounds__(256) void gemm_k(const float* __restrict__ A, int lda,
                                              const float* __restrict__ Bm, int ldb,
                                              float* __restrict__ C, int ldc,
                                              int N, int K,
                                              const float* __restrict__ bias1,
                                              const float* __restrict__ bias2,
                                              int do_relu)
{
    gemm_body<TM>(A, lda, Bm, ldb, C, ldc, N, K, bias1, bias2, do_relu,
                  blockIdx.x * TM, blockIdx.y * 64);
}

template<int TM>
__global__ __launch_bounds__(256) void gemm_dual_k(const float* __restrict__ A0, const float* __restrict__ A1, int lda,
                                                   const float* __restrict__ B0, const float* __restrict__ B1, int ldb,
                                                   float* __restrict__ C0, float* __restrict__ C1, int ldc,
                                                   int N, int K,
                                                   const float* __restrict__ bias0, const float* __restrict__ bias1,
                                                   int do_relu)
{
    const int z = blockIdx.z;
    gemm_body<TM>(z ? A1 : A0, lda, z ? B1 : B0, ldb, z ? C1 : C0, ldc, N, K,
                  z ? bias1 : bias0, nullptr, do_relu, blockIdx.x * TM, blockIdx.y * 64);
}

// ---------------------------------------------------------------- xW GEMM with fused token-gather
__global__ __launch_bounds__(256) void gemm_emb_k(const int* __restrict__ tokens,
                                                  const float* __restrict__ word_emb,
                                                  const float* __restrict__ B0, const float* __restrict__ B1,
                                                  float* __restrict__ C0, float* __restrict__ C1,
                                                  const float* __restrict__ bi0a, const float* __restrict__ bi0b,
                                                  const float* __restrict__ bi1a, const float* __restrict__ bi1b)
{
    __shared__ float As[16][132];
    __shared__ float Bs[16][68];
    const int z = blockIdx.z;
    const float* Bm = z ? B1 : B0;
    float* C       = z ? C1 : C0;
    const float* ba = z ? bi1a : bi0a;
    const float* bb = z ? bi1b : bi0b;
    const int t = threadIdx.x;
    const int m_blk = blockIdx.x * 128;
    const int n_blk = blockIdx.y * 64;
    const int tm = (t >> 4) * 8;
    const int tn = (t & 15) * 4;
    float acc[8][4];
    #pragma unroll
    for (int i=0;i<8;++i){ acc[i][0]=0.f; acc[i][1]=0.f; acc[i][2]=0.f; acc[i][3]=0.f; }

    for (int ck = 0; ck < 19; ++ck){
        const int k0 = ck << 4;
        __syncthreads();
        #pragma unroll
        for (int it = 0; it < 2; ++it){
            int task = t + it*256;
            int m = task >> 2, q = task & 3;
            int kk = k0 + q*4;
            const int tok = tokens[m_blk + m];
            const float* ap = word_emb + (size_t)tok*ED + kk;
            float4 v = make_float4(0.f,0.f,0.f,0.f);
            if (kk + 3 < ED) v = *(const float4*)ap;
            else {
                if (kk   < ED) v.x = ap[0];
                if (kk+1 < ED) v.y = ap[1];
                if (kk+2 < ED) v.z = ap[2];
            }
            As[q*4+0][m] = v.x; As[q*4+1][m] = v.y; As[q*4+2][m] = v.z; As[q*4+3][m] = v.w;
        }
        {
            int n = t >> 2, q = t & 3;
            int kk = k0 + q*4;
            const float* bp = Bm + (size_t)(n_blk + n)*ED + kk;
            float4 v = make_float4(0.f,0.f,0.f,0.f);
            if (kk + 3 < ED) v = *(const float4*)bp;
            else {
                if (kk   < ED) v.x = bp[0];
                if (kk+1 < ED) v.y = bp[1];
                if (kk+2 < ED) v.z = bp[2];
            }
            Bs[q*4+0][n] = v.x; Bs[q*4+1][n] = v.y; Bs[q*4+2][n] = v.z; Bs[q*4+3][n] = v.w;
        }
        __syncthreads();
        #pragma unroll
        for (int k = 0; k < 16; ++k){
            float4 b4 = *(const float4*)&Bs[k][tn];
            float bn[4] = {b4.x, b4.y, b4.z, b4.w};
            #pragma unroll
            for (int i = 0; i < 2; ++i){
                float4 a4 = *(const float4*)&As[k][tm + i*4];
                float am[4] = {a4.x, a4.y, a4.z, a4.w};
                #pragma unroll
                for (int mm = 0; mm < 4; ++mm){
                    #pragma unroll
                    for (int nn = 0; nn < 4; ++nn)
                        acc[i*4+mm][nn] += am[mm]*bn[nn];
                }
            }
        }
    }
    float bv[4];
    #pragma unroll
    for (int nn=0;nn<4;++nn){ int gn = n_blk + tn + nn; bv[nn] = ba[gn] + bb[gn]; }
    #pragma unroll
    for (int mm = 0; mm < 8; ++mm){
        int gm = m_blk + tm + mm;
        *(float4*)(C + (size_t)gm*G4 + n_blk + tn) =
            make_float4(acc[mm][0]+bv[0], acc[mm][1]+bv[1], acc[mm][2]+bv[2], acc[mm][3]+bv[3]);
    }
}

// ---------------------------------------------------------------- LSTM exchange helpers (agent scope, via IC)
__device__ __forceinline__ unsigned long long agld(const unsigned long long* p){
    return __hip_atomic_load(p, __ATOMIC_RELAXED, __HIP_MEMORY_SCOPE_AGENT);
}
__device__ __forceinline__ void agst(unsigned long long* p, unsigned long long v){
    __hip_atomic_store(p, v, __ATOMIC_RELAXED, __HIP_MEMORY_SCOPE_AGENT);
}
__device__ __forceinline__ bool tagok(unsigned long long a, unsigned long long b,
                                      unsigned long long c, unsigned long long d, unsigned w){
    return ((unsigned)(a>>32)==w) & ((unsigned)(b>>32)==w) &
           ((unsigned)(c>>32)==w) & ((unsigned)(d>>32)==w);
}

// ---------------------------------------------------------------- direction-split LSTM
// 512 wgs = 8 teams x 32 ranks x 2 dirs; each wg handles ONE direction of a
// batch-pair team (rank owns hidden [rank*16,+16)). Halving per-wg weight
// residency (128 f32/thread vs 256) brings regs under 256 -> 2 wgs/CU
// (launch_bounds(256,2)). dir = wg>>8: dispatch sweep 1 = all fwd wgs on 256
// CUs, sweep 2 pairs each CU with a bwd wg — an INDEPENDENT recurrence. When
// one wg spins on the IC exchange (~3.3k cyc, invariant per r0/r3 rocprof),
// the co-resident wg's 4 waves own the VALU. Period model: max(C+W, 2C) ~
// 5.5k cyc/step vs baseline 10k. Exchange protocol identical to the proven
// baseline: packed u64 (tag<<32|float_bits), relaxed agent atomics, parity
// double-buffer, memset-0 gives step-0 tags. (R3 lesson: chains inside ONE
// wg cannot overlap — one instruction stream, one barrier domain.)
__global__ __launch_bounds__(256, 2) void lstm_k(const float* __restrict__ xwf,
                                                 const float* __restrict__ xwb,
                                                 const float* __restrict__ whhf,
                                                 const float* __restrict__ whhb,
                                                 unsigned long long* __restrict__ hteam, // 8*2*2*1024 u64
                                                 float* __restrict__ hf_all,
                                                 float* __restrict__ hb_all)
{
    __shared__ __align__(16) float h_s[2*HD];      // 4 KB staging (2 batches)
    __shared__ __align__(16) float part[8*128];    // 4 KB [kc][row*2+b]
    __shared__ float gates_s[128];                 // [row*2+b]
    __shared__ float cst[32];                      // [hid*2+b]
    const int wg   = blockIdx.x;
    const int dir  = wg >> 8;                      // 0 = fwd, 1 = bwd
    const int id8  = wg & 255;
    const int team = id8 >> 5;                     // 0..7
    const int rank = id8 & 31;
    const int b0   = team * 2;
    const int t    = threadIdx.x;
    const int wv   = t >> 6;
    const int lane = t & 63;
    const int rg   = t & 31;
    const int kc   = t >> 5;                       // 0..7 (64 k each)
    const int lr0  = rg*2, lr1 = rg*2 + 1;
    const int grow0 = (lr0 >> 4)*HD + rank*16 + (lr0 & 15);
    const int grow1 = (lr1 >> 4)*HD + rank*16 + (lr1 & 15);
    const float* xw   = dir ? xwb    : xwf;
    const float* whh  = dir ? whhb   : whhf;
    float*       hall = dir ? hb_all : hf_all;
    unsigned long long* hT = hteam + (size_t)((team*2 + dir)*2)*1024;

    // ---- one-time: this dir's weight slice into registers (32 float4 = 128 VGPRs) ----
    float4 w0[16], w1[16];
    {
        const float* p0 = whh + (size_t)grow0*HD + kc*64;
        const float* p1 = whh + (size_t)grow1*HD + kc*64;
        #pragma unroll
        for (int q = 0; q < 16; ++q){
            w0[q] = *(const float4*)(p0 + q*4);
            w1[q] = *(const float4*)(p1 + q*4);
        }
    }
    // reduce mapping (t<128): entry = row*2 + b
    const int rrow = t >> 1, rb2 = t & 1;
    const int growr = (rrow >> 4)*HD + rank*16 + (rrow & 15);
    // activation mapping (t<32)
    const int ahl = t >> 1, ab2 = t & 1;
    const int hidx_a = rank*16 + ahl;
    // staging slots (4 u64/thread): b in {0,1}, halves {0,64}
    const int s0 = wv*128 + lane;

    if (t < 32) cst[t] = 0.f;
    __syncthreads();

    int par = 0;
    for (int s = 0; s < SL; ++s){
        const unsigned want = (unsigned)s;          // s=0 tags come from memset(0)
        const int sx = dir ? (SL-1 - s) : s;
        float xval = 0.f;
        if (t < 128)                                // issue early: in flight during poll
            xval = xw[(size_t)((b0 + rb2)*SL + sx)*G4 + growr];
        // ---- poll + stage ----
        {
            const unsigned long long* src = hT + (size_t)par*1024;
            unsigned long long v0, v1, v2, v3;
            for (;;){
                v0 = agld(&src[      s0     ]);
                v1 = agld(&src[      s0 + 64]);
                v2 = agld(&src[512 + s0     ]);
                v3 = agld(&src[512 + s0 + 64]);
                if (tagok(v0,v1,v2,v3,want)) break;
                __builtin_amdgcn_s_sleep(1);
            }
            h_s[     s0     ] = __uint_as_float((unsigned)v0);
            h_s[     s0 + 64] = __uint_as_float((unsigned)v1);
            h_s[HD + s0     ] = __uint_as_float((unsigned)v2);
            h_s[HD + s0 + 64] = __uint_as_float((unsigned)v3);
        }
        // ---- partials: 2 rows x 2 batches x 64 k ----
        {
            float a00=0.f,a01=0.f,a10=0.f,a11=0.f;
            #pragma unroll
            for (int q = 0; q < 16; ++q){
                float4 wa = w0[q], wb = w1[q];
                float4 h0 = *(const float4*)(h_s + 0*HD + kc*64 + q*4);
                float4 h1 = *(const float4*)(h_s + 1*HD + kc*64 + q*4);
                a00 += wa.x*h0.x + wa.y*h0.y + wa.z*h0.z + wa.w*h0.w;
                a01 += wa.x*h1.x + wa.y*h1.y + wa.z*h1.z + wa.w*h1.w;
                a10 += wb.x*h0.x + wb.y*h0.y + wb.z*h0.z + wb.w*h0.w;
                a11 += wb.x*h1.x + wb.y*h1.y + wb.z*h1.z + wb.w*h1.w;
            }
            *(float4*)&part[kc*128 + lr0*2] = make_float4(a00,a01,a10,a11);
        }
        __syncthreads();
        if (t < 128){
            float g = 0.f;
            #pragma unroll
            for (int c = 0; c < 8; ++c) g += part[c*128 + t];
            gates_s[t] = g + xval;
        }
        __syncthreads();
        if (t < 32){
            float gi  = gates_s[(0*16 + ahl)*2 + ab2];
            float gf  = gates_s[(1*16 + ahl)*2 + ab2];
            float gc  = gates_s[(2*16 + ahl)*2 + ab2];
            float go_ = gates_s[(3*16 + ahl)*2 + ab2];
            float cp = cst[t];
            float cn = sigf(gf)*cp + sigf(gi)*tanhf(gc);
            float hn = sigf(go_)*tanhf(cn);
            cst[t] = cn;
            unsigned long long pk = ((unsigned long long)(unsigned)(s+1) << 32)
                                  | (unsigned long long)__float_as_uint(hn);
            agst(&hT[(size_t)(par^1)*1024 + ab2*512 + hidx_a], pk);
            hall[(size_t)((b0 + ab2)*SL + sx)*HD + hidx_a] = hn;
        }
        par ^= 1;
    }
}

// ---------------------------------------------------------------- combine o | bio_emb
__global__ __launch_bounds__(256) void combine_k(const float* __restrict__ hf,
                                                 const float* __restrict__ hb,
                                                 const int* __restrict__ bio_gold,
                                                 const float* __restrict__ bio_emb,
                                                 float* __restrict__ oc)
{
    int idx = blockIdx.x*256 + threadIdx.x;
    if (idx >= NTOK*144) return;
    int row = idx / 144;
    int c4 = (idx - row*144) * 4;
    float4 v;
    if (c4 < HD){
        float4 a = *(const float4*)(hf + (size_t)row*HD + c4);
        float4 b = *(const float4*)(hb + (size_t)row*HD + c4);
        v = make_float4(0.5f*(a.x+b.x), 0.5f*(a.y+b.y), 0.5f*(a.z+b.z), 0.5f*(a.w+b.w));
    } else {
        int bg = bio_gold[row];
        v = *(const float4*)(bio_emb + bg*BE + (c4 - HD));
    }
    *(float4*)(oc + (size_t)row*OCD + c4) = v;
}

// ---------------------------------------------------------------- CRF NLL (wave-sync) + msum
__global__ __launch_bounds__(64) void crf_k(const float* __restrict__ emi,
                                            const int* __restrict__ tags,
                                            const int* __restrict__ tokens,
                                            const float* __restrict__ trans,
                                            const float* __restrict__ startv,
                                            const float* __restrict__ endv,
                                            float* __restrict__ out_crf,
                                            float* __restrict__ out_m)
{
    const int b = blockIdx.x, lane = threadIdx.x;
    unsigned long long m0 = __ballot(tokens[b*SL + lane] != 0);
    unsigned long long m1 = __ballot(tokens[b*SL + 64 + lane] != 0);
    const int len = __popcll(m0) + __popcll(m1);
    float npart = 0.f;
    #pragma unroll
    for (int half = 0; half < 2; ++half){
        int tt = lane + half*64;
        if (tt >= 1 && tt < len){
            int tp = tags[b*SL + tt - 1], tc = tags[b*SL + tt];
            npart += trans[tp*NT + tc] + emi[(size_t)(b*SL + tt)*NT + tc];
        }
    }
    #pragma unroll
    for (int off = 32; off > 0; off >>= 1) npart += __shfl_down(npart, off);
    float tr[NT]; float alpha = -1e30f;
    if (lane < NT){
        #pragma unroll
        for (int i = 0; i < NT; ++i) tr[i] = trans[i*NT + lane];
        alpha = startv[lane] + emi[(size_t)(b*SL)*NT + lane];
    }
    for (int tt = 1; tt < SL; ++tt){
        float al[NT];
        #pragma unroll
        for (int i = 0; i < NT; ++i) al[i] = __shfl(alpha, i);
        if (lane < NT && tt < len){
            float mx = -1e30f;
            #pragma unroll
            for (int i = 0; i < NT; ++i) mx = fmaxf(mx, al[i] + tr[i]);
            float se = 0.f;
            #pragma unroll
            for (int i = 0; i < NT; ++i) se += __expf(al[i] + tr[i] - mx);
            alpha = mx + __logf(se) + emi[(size_t)(b*SL + tt)*NT + lane];
        }
    }
    float alf = (lane < NT) ? (alpha + endv[lane]) : -1e30f;
    float alE[NT];
    #pragma unroll
    for (int i = 0; i < NT; ++i) alE[i] = __shfl(alf, i);
    if (lane == 0){
        float mx = -1e30f;
        #pragma unroll
        for (int i = 0; i < NT; ++i) mx = fmaxf(mx, alE[i]);
        float se = 0.f;
        #pragma unroll
        for (int i = 0; i < NT; ++i) se += __expf(alE[i] - mx);
        float den = mx + __logf(se);
        int t0g = tags[b*SL];
        float num = startv[t0g] + emi[(size_t)(b*SL)*NT + t0g] + npart;
        num += endv[tags[b*SL + len - 1]];
        atomicAdd(out_crf, -(num - den) * (1.0f/16.0f));
        atomicAdd(out_m, (float)len);
    }
}

// ---------------------------------------------------------------- fused uv->logits->BCE
__global__ __launch_bounds__(256) void sel_k(const float* __restrict__ U2,
                                             const float* __restrict__ V2,
                                             const float* __restrict__ uvb,
                                             const float* __restrict__ rel_emb,
                                             const int* __restrict__ gold,
                                             const int* __restrict__ tokens,
                                             float* __restrict__ out_sel)
{
    __shared__ float ret_s[RE][52];
    __shared__ float pt_s[RE][68];
    __shared__ float vb_s[RE];
    __shared__ float mk_s[64];
    __shared__ float red_s[4];
    const int jt = blockIdx.x, qi = blockIdx.y, b = blockIdx.z;
    const int t = threadIdx.x;
    if (tokens[b*SL + qi] == 0) return;
    if (t < 32){
        float4 v4 = *(const float4*)(V2 + (size_t)(b*SL + qi)*RE + t*4);
        float4 b4 = *(const float4*)(uvb + t*4);
        vb_s[t*4+0] = v4.x + b4.x; vb_s[t*4+1] = v4.y + b4.y;
        vb_s[t*4+2] = v4.z + b4.z; vb_s[t*4+3] = v4.w + b4.w;
    }
    if (t < 64) mk_s[t] = (tokens[b*SL + jt*64 + t] != 0) ? 1.f : 0.f;
    {
        int r = t & 63;
        for (int q = t >> 6; q < 32; q += 4){
            if (r < NR){
                float4 e4 = *(const float4*)(rel_emb + (size_t)r*RE + q*4);
                ret_s[q*4+0][r] = e4.x; ret_s[q*4+1][r] = e4.y;
                ret_s[q*4+2][r] = e4.z; ret_s[q*4+3][r] = e4.w;
            } else if (r < 64){
                ret_s[q*4+0][r] = 0.f; ret_s[q*4+1][r] = 0.f;
                ret_s[q*4+2][r] = 0.f; ret_s[q*4+3][r] = 0.f;
            }
        }
    }
    __syncthreads();
    {
        int j = t & 63;
        for (int q = t >> 6; q < 32; q += 4){
            float4 u4 = *(const float4*)(U2 + (size_t)(b*SL + jt*64 + j)*RE + q*4);
            pt_s[q*4+0][j] = fmaxf(u4.x + vb_s[q*4+0], 0.f);
            pt_s[q*4+1][j] = fmaxf(u4.y + vb_s[q*4+1], 0.f);
            pt_s[q*4+2][j] = fmaxf(u4.z + vb_s[q*4+2], 0.f);
            pt_s[q*4+3][j] = fmaxf(u4.w + vb_s[q*4+3], 0.f);
        }
    }
    __syncthreads();
    const int mj = (t & 15) * 4;
    const int nr = (t >> 4) * 4;
    float accv[4][4];
    #pragma unroll
    for (int i=0;i<4;++i){ accv[i][0]=0.f; accv[i][1]=0.f; accv[i][2]=0.f; accv[i][3]=0.f; }
    #pragma unroll 4
    for (int k = 0; k < RE; ++k){
        float4 aj = *(const float4*)&pt_s[k][mj];
        float4 br = *(const float4*)&ret_s[k][nr];
        float am[4] = {aj.x, aj.y, aj.z, aj.w};
        float bn[4] = {br.x, br.y, br.z, br.w};
        #pragma unroll
        for (int mm = 0; mm < 4; ++mm){
            #pragma unroll
            for (int nn = 0; nn < 4; ++nn)
                accv[mm][nn] += am[mm]*bn[nn];
        }
    }
    float lsum = 0.f;
    #pragma unroll
    for (int nn = 0; nn < 4; ++nn){
        int r = nr + nn;
        if (r < NR){
            const int* gp = gold + (size_t)((b*SL + qi)*NR + r)*SL + jt*64 + mj;
            #pragma unroll
            for (int mm = 0; mm < 4; ++mm){
                float l = accv[mm][nn];
                float g = (float)gp[mm];
                float bce = fmaxf(l, 0.f) - l*g + __logf(1.f + __expf(-fabsf(l)));
                lsum += bce * mk_s[mj + mm];
            }
        }
    }
    #pragma unroll
    for (int off = 32; off > 0; off >>= 1) lsum += __shfl_down(lsum, off);
    if ((t & 63) == 0) red_s[t >> 6] = lsum;
    __syncthreads();
    if (t == 0) atomicAdd(out_sel, red_s[0]+red_s[1]+red_s[2]+red_s[3]);
}

// ---------------------------------------------------------------- finalize
__global__ void finalize_k(const float* __restrict__ accum, float* __restrict__ out)
{
    if (threadIdx.x == 0 && blockIdx.x == 0) out[0] = accum[0] + accum[1] / accum[2];
}

// ---------------------------------------------------------------- launch
extern "C" void kernel_launch(void* const* d_in, const int* in_sizes, int n_in,
                              void* d_out, int out_size, void* d_ws, size_t ws_size,
                              hipStream_t stream)
{
    const int*   tokens    = (const int*)  d_in[0];
    const int*   bio_gold  = (const int*)  d_in[1];
    const int*   sel_gold  = (const int*)  d_in[2];
    const float* word_emb  = (const float*)d_in[4];
    const float* rel_emb   = (const float*)d_in[5];
    const float* bio_emb   = (const float*)d_in[6];
    const float* w_ih_f    = (const float*)d_in[7];
    const float* w_hh_f    = (const float*)d_in[8];
    const float* b_ih_f    = (const float*)d_in[9];
    const float* b_hh_f    = (const float*)d_in[10];
    const float* w_ih_b    = (const float*)d_in[11];
    const float* w_hh_b    = (const float*)d_in[12];
    const float* b_ih_b    = (const float*)d_in[13];
    const float* b_hh_b    = (const float*)d_in[14];
    const float* emission_w= (const float*)d_in[15];
    const float* emission_b= (const float*)d_in[16];
    const float* sel_u_w   = (const float*)d_in[17];
    const float* sel_u_b   = (const float*)d_in[18];
    const float* sel_v_w   = (const float*)d_in[19];
    const float* sel_v_b   = (const float*)d_in[20];
    const float* sel_uv_w  = (const float*)d_in[21];
    const float* sel_uv_b  = (const float*)d_in[22];
    const float* crf_trans = (const float*)d_in[23];
    const float* crf_start = (const float*)d_in[24];
    const float* crf_end   = (const float*)d_in[25];
    (void)in_sizes; (void)n_in; (void)out_size; (void)ws_size;

    float* ws     = (float*)d_ws;
    float* emb    = ws;                         // region reused for hteam
    float* xwf    = emb    + (size_t)NTOK*ED;
    float* xwb    = xwf    + (size_t)NTOK*G4;
    float* hf_all = xwb    + (size_t)NTOK*G4;
    float* hb_all = hf_all + (size_t)NTOK*HD;
    float* oc     = hb_all + (size_t)NTOK*HD;
    float* emi    = oc     + (size_t)NTOK*OCD;
    float* u_     = emi    + (size_t)NTOK*NT;
    float* v_     = u_     + (size_t)NTOK*RE;
    float* U2     = v_     + (size_t)NTOK*RE;
    float* V2     = U2     + (size_t)NTOK*RE;
    float* accum  = V2     + (size_t)NTOK*RE;   // [0]=crf, [1]=sel_sum, [2]=msum, [3]=pad

    // packed h exchange: 8 teams x 2 dirs x 2 parities x 1024 u64 = 256 KB
    unsigned long long* hteam = (unsigned long long*)emb;

    hipMemsetAsync(accum, 0, 4*sizeof(float), stream);
    hipMemsetAsync(hteam, 0, (size_t)8*2*2*1024*sizeof(unsigned long long), stream);

    // fused gather + xW GEMM, both directions in one dispatch
    gemm_emb_k<<<dim3(NTOK/128, G4/64, 2), 256, 0, stream>>>(tokens, word_emb,
                                                             w_ih_f, w_ih_b, xwf, xwb,
                                                             b_ih_f, b_hh_f, b_ih_b, b_hh_b);

    {
        const float *p_xwf = xwf, *p_xwb = xwb, *p_whf = w_hh_f, *p_whb = w_hh_b;
        unsigned long long* p_ht = hteam;
        float *p_hf = hf_all, *p_hb = hb_all;
        void* args[7] = {&p_xwf, &p_xwb, &p_whf, &p_whb, &p_ht, &p_hf, &p_hb};
        hipLaunchCooperativeKernel(lstm_k, dim3(512), dim3(256), args, 0u, stream);
    }

    combine_k<<<(NTOK*144 + 255)/256, 256, 0, stream>>>(hf_all, hb_all, bio_gold, bio_emb, oc);

    gemm_k<64><<<dim3(NTOK/64, 1), 256, 0, stream>>>(oc, OCD, emission_w, HD, emi, NT, NT, HD, emission_b, nullptr, 0);
    gemm_dual_k<64><<<dim3(NTOK/64, 2, 2), 256, 0, stream>>>(oc, oc, OCD, sel_u_w, sel_v_w, OCD,
                                                             u_, v_, RE, RE, OCD, sel_u_b, sel_v_b, 1);
    gemm_dual_k<64><<<dim3(NTOK/64, 2, 2), 256, 0, stream>>>(u_, v_, RE, sel_uv_w, sel_uv_w + RE, 2*RE,
                                                             U2, V2, RE, RE, RE, nullptr, nullptr, 0);

    crf_k<<<NB, 64, 0, stream>>>(emi, bio_gold, tokens, crf_trans, crf_start, crf_end, accum + 0, accum + 2);
    sel_k<<<dim3(2, SL, NB), 256, 0, stream>>>(U2, V2, sel_uv_b, rel_emb, sel_gold, tokens, accum + 1);

    finalize_k<<<1, 1, 0, stream>>>(accum, (float*)d_out);
}